// Round 4
// baseline (395.104 us; speedup 1.0000x reference)
//
#include <hip/hip_runtime.h>
#include <math.h>

#define Bsz 4
#define T 2048
#define D 128
#define H 8
#define HS 16
#define E 8
#define FF 512
#define N (Bsz*T)     // 8192
#define NQ (Bsz*H*T)  // 65536 query rows
#define EPS 1e-5f
#define SCALE 0.25f   // 1/sqrt(16)
#define SPLITS 8

typedef _Float16 h4 __attribute__((ext_vector_type(4)));
typedef _Float16 h2 __attribute__((ext_vector_type(2)));
typedef float f4 __attribute__((ext_vector_type(4)));
#define MFMA16 __builtin_amdgcn_mfma_f32_16x16x16f16

__device__ __forceinline__ float wave_sum(float v) {
#pragma unroll
  for (int off = 32; off >= 1; off >>= 1) v += __shfl_xor(v, off);
  return v;
}

// ---------------- LayerNorm: one wave per row of 128 (optional f16 copy) ----------------
__global__ void ln_kernel(const float* __restrict__ x, const float* __restrict__ g,
                          const float* __restrict__ b, float* __restrict__ out,
                          _Float16* __restrict__ outh) {
  int n = blockIdx.x;
  int tid = threadIdx.x;  // 64
  float2 v = ((const float2*)(x + n * D))[tid];
  float s  = wave_sum(v.x + v.y);
  float s2 = wave_sum(v.x * v.x + v.y * v.y);
  float m = s * (1.f / D);
  float var = s2 * (1.f / D) - m * m;
  float r = rsqrtf(var + EPS);
  float2 gg = ((const float2*)g)[tid];
  float2 bb = ((const float2*)b)[tid];
  float2 o;
  o.x = (v.x - m) * r * gg.x + bb.x;
  o.y = (v.y - m) * r * gg.y + bb.y;
  ((float2*)(out + n * D))[tid] = o;
  if (outh) {
    h2 hv = {(_Float16)o.x, (_Float16)o.y};
    ((h2*)(outh + n * D))[tid] = hv;
  }
}

// ---------------- tiled transpose + f32->f16: in[e][R][C] -> out[e][C][R] ----------------
__global__ void transpose_f16(const float* __restrict__ in, _Float16* __restrict__ out,
                              int R, int C) {
  __shared__ float tile[32][33];
  int e = blockIdx.z;
  int tc = blockIdx.x * 32;
  int tr = blockIdx.y * 32;
  const float* src = in + (size_t)e * R * C;
  _Float16* dst = out + (size_t)e * R * C;
  int lx = threadIdx.x & 31, ly = threadIdx.x >> 5;  // 256 thr: ly 0..7
#pragma unroll
  for (int i = 0; i < 32; i += 8)
    tile[ly + i][lx] = src[(size_t)(tr + ly + i) * C + tc + lx];
  __syncthreads();
#pragma unroll
  for (int i = 0; i < 32; i += 8)
    dst[(size_t)(tc + ly + i) * R + tr + lx] = (_Float16)tile[lx][ly + i];
}

// ---------------- QKV: 16 tokens/block, 384 threads; f16 outputs ----------------
__global__ void qkv_kernel(const float* __restrict__ xn, const float* __restrict__ wq,
                           const float* __restrict__ wk, const float* __restrict__ wv,
                           _Float16* __restrict__ qh, _Float16* __restrict__ kh,
                           _Float16* __restrict__ vTh) {
  __shared__ float xs[D][20];
  int n0 = blockIdx.x * 16;
  int tid = threadIdx.x;
  for (int idx = tid; idx < 16 * D; idx += 384) {
    int t = idx >> 7, d = idx & 127;
    xs[d][t] = xn[(n0 + t) * D + d];
  }
  __syncthreads();
  int grp = tid / 128;        // 0=q 1=k 2=v (wave-uniform)
  int o = tid & 127;
  int h = o >> 4, e = o & 15;
  const float* w = (grp == 0 ? wq : (grp == 1 ? wk : wv)) + h * D * HS + e;
  float acc[16];
#pragma unroll
  for (int t = 0; t < 16; ++t) acc[t] = 0.f;
  for (int d = 0; d < D; ++d) {
    float wv_ = w[d * HS];
    float4 a0 = *(const float4*)&xs[d][0];
    float4 a1 = *(const float4*)&xs[d][4];
    float4 a2 = *(const float4*)&xs[d][8];
    float4 a3 = *(const float4*)&xs[d][12];
    float xv[16] = {a0.x,a0.y,a0.z,a0.w, a1.x,a1.y,a1.z,a1.w,
                    a2.x,a2.y,a2.z,a2.w, a3.x,a3.y,a3.z,a3.w};
#pragma unroll
    for (int t = 0; t < 16; ++t) acc[t] += wv_ * xv[t];
  }
  int b_ = n0 / T, t0 = n0 % T;
  if (grp == 0) {
    _Float16* dq = qh + ((size_t)(b_ * H + h) * T + t0) * 16 + e;
#pragma unroll
    for (int t = 0; t < 16; ++t) dq[t * 16] = (_Float16)(acc[t] * SCALE);
  } else if (grp == 1) {
    _Float16* dk = kh + ((size_t)(b_ * H + h) * T + t0) * 16 + e;
#pragma unroll
    for (int t = 0; t < 16; ++t) dk[t * 16] = (_Float16)acc[t];
  } else {
    _Float16* dv = vTh + ((size_t)(b_ * H + h) * 16 + e) * T + t0;
#pragma unroll
    for (int t = 0; t < 16; ++t) dv[t] = (_Float16)acc[t];
  }
}

// ---------------- MFMA flash attention partial ----------------
__global__ __launch_bounds__(64) void attn_mfma(
    const _Float16* __restrict__ q, const _Float16* __restrict__ k,
    const _Float16* __restrict__ vT, float* __restrict__ part) {
  int bh = blockIdx.y;
  int qt = blockIdx.x >> 3;     // 0..31 (64 queries)
  int s  = blockIdx.x & 7;      // split: keys [256s, 256s+256)
  int glo = 4 * s;
  int ghi = min(glo + 4, qt + 1);
  if (glo >= ghi) return;
  int l = threadIdx.x;
  int lg = l >> 4, lr = l & 15;
  int q0 = qt * 64;
  const h4* qp = (const h4*)(q + ((size_t)bh * T + q0 + lr) * 16 + 4 * lg);
  h4 qf[4];
#pragma unroll
  for (int nt = 0; nt < 4; ++nt) qf[nt] = qp[nt * 64];
  f4 o0 = {0.f,0.f,0.f,0.f}, o1 = o0, o2 = o0, o3 = o0;
  float m0 = -1e30f, m1 = -1e30f, m2 = -1e30f, m3 = -1e30f;
  float l0 = 0.f, l1 = 0.f, l2 = 0.f, l3 = 0.f;
  for (int g = glo; g < ghi; ++g) {
    int k0g = g * 64;
    const h4* kp = (const h4*)(k + ((size_t)bh * T + k0g + lr) * 16 + 4 * lg);
    h4 kf[4];
#pragma unroll
    for (int mt = 0; mt < 4; ++mt) kf[mt] = kp[mt * 64];
    const h4* vp = (const h4*)(vT + ((size_t)bh * 16 + lr) * T + k0g + 4 * lg);
    h4 vf[4];
#pragma unroll
    for (int mt = 0; mt < 4; ++mt) vf[mt] = vp[mt * 4];
    f4 z = {0.f,0.f,0.f,0.f};
    f4 sc[4][4];
#pragma unroll
    for (int mt = 0; mt < 4; ++mt)
#pragma unroll
      for (int nt = 0; nt < 4; ++nt)
        sc[mt][nt] = MFMA16(kf[mt], qf[nt], z, 0, 0, 0);
    if (g == qt) {  // diagonal tile: mask key > query
#pragma unroll
      for (int mt = 0; mt < 4; ++mt)
#pragma unroll
        for (int nt = 0; nt < 4; ++nt) {
          int kb = 16 * mt + 4 * lg, qb = 16 * nt + lr;
          if (kb + 0 > qb) sc[mt][nt].x = -1e30f;
          if (kb + 1 > qb) sc[mt][nt].y = -1e30f;
          if (kb + 2 > qb) sc[mt][nt].z = -1e30f;
          if (kb + 3 > qb) sc[mt][nt].w = -1e30f;
        }
    }
#define PROC(NT, M, L, O) do { \
    float tm = -1e30f; \
    _Pragma("unroll") for (int mt = 0; mt < 4; ++mt) { \
      f4 a = sc[mt][NT]; \
      tm = fmaxf(tm, fmaxf(fmaxf(a.x, a.y), fmaxf(a.z, a.w))); } \
    tm = fmaxf(tm, __shfl_xor(tm, 16)); \
    tm = fmaxf(tm, __shfl_xor(tm, 32)); \
    float mn = fmaxf(M, tm); \
    float c = __expf(M - mn); M = mn; L *= c; \
    O.x *= c; O.y *= c; O.z *= c; O.w *= c; \
    float sum = 0.f; h4 pf[4]; \
    _Pragma("unroll") for (int mt = 0; mt < 4; ++mt) { \
      f4 a = sc[mt][NT]; h4 p; float ex; \
      ex = __expf(a.x - mn); sum += ex; p.x = (_Float16)ex; \
      ex = __expf(a.y - mn); sum += ex; p.y = (_Float16)ex; \
      ex = __expf(a.z - mn); sum += ex; p.z = (_Float16)ex; \
      ex = __expf(a.w - mn); sum += ex; p.w = (_Float16)ex; \
      pf[mt] = p; } \
    sum += __shfl_xor(sum, 16); sum += __shfl_xor(sum, 32); L += sum; \
    _Pragma("unroll") for (int mt = 0; mt < 4; ++mt) \
      O = MFMA16(vf[mt], pf[mt], O, 0, 0, 0); \
  } while (0)
    PROC(0, m0, l0, o0);
    PROC(1, m1, l1, o1);
    PROC(2, m2, l2, o2);
    PROC(3, m3, l3, o3);
#undef PROC
  }
  float* pb = part + (size_t)s * 18 * NQ;
  int nbase = bh * T + q0 + lr;
#define WR(NT, M, L, O) do { int n = nbase + 16 * NT; \
    pb[(4 * lg + 0) * NQ + n] = O.x; pb[(4 * lg + 1) * NQ + n] = O.y; \
    pb[(4 * lg + 2) * NQ + n] = O.z; pb[(4 * lg + 3) * NQ + n] = O.w; \
    if (lg == 0) { pb[16 * NQ + n] = M; pb[17 * NQ + n] = L; } \
  } while (0)
  WR(0, m0, l0, o0);
  WR(1, m1, l1, o1);
  WR(2, m2, l2, o2);
  WR(3, m3, l3, o3);
#undef WR
}

// ---------------- attention combine: lane = one query row ----------------
__global__ void attn_comb(const float* __restrict__ part, float* __restrict__ ao) {
  int n = blockIdx.x * 64 + threadIdx.x;   // 0..NQ-1
  int t = n & (T - 1);
  int ns = (t >> 8) + 1;                   // splits with any keys <= t
  float m = -1e30f;
  for (int s = 0; s < ns; ++s)
    m = fmaxf(m, part[(s * 18 + 16) * NQ + n]);
  float acc[16];
#pragma unroll
  for (int e = 0; e < 16; ++e) acc[e] = 0.f;
  float L = 0.f;
  for (int s = 0; s < ns; ++s) {
    float w = __expf(part[(s * 18 + 16) * NQ + n] - m);
    L += w * part[(s * 18 + 17) * NQ + n];
#pragma unroll
    for (int e = 0; e < 16; ++e)
      acc[e] += w * part[(s * 18 + e) * NQ + n];
  }
  float inv = 1.f / L;
  int bh = n >> 11, b = bh >> 3, h = bh & 7;
  float* op = ao + ((size_t)(b * T + t) * D) + h * HS;
#pragma unroll
  for (int r = 0; r < 4; ++r) {
    float4 o4 = {acc[4*r]*inv, acc[4*r+1]*inv, acc[4*r+2]*inv, acc[4*r+3]*inv};
    ((float4*)op)[r] = o4;
  }
}

// ---------------- proj + bias + residual ----------------
__global__ void proj_kernel(const float* __restrict__ attn, const float* __restrict__ wp,
                            const float* __restrict__ bp, const float* __restrict__ x,
                            float* __restrict__ x1) {
  __shared__ float as_[D][20];
  int n0 = blockIdx.x * 16;
  int tid = threadIdx.x;  // 128
  for (int idx = tid; idx < 16 * D; idx += 128) {
    int t = idx >> 7, d = idx & 127;
    as_[d][t] = attn[(n0 + t) * D + d];
  }
  __syncthreads();
  float acc[16];
#pragma unroll
  for (int t = 0; t < 16; ++t) acc[t] = 0.f;
  for (int d = 0; d < D; ++d) {
    float w = wp[d * D + tid];
    float4 a0 = *(const float4*)&as_[d][0];
    float4 a1 = *(const float4*)&as_[d][4];
    float4 a2 = *(const float4*)&as_[d][8];
    float4 a3 = *(const float4*)&as_[d][12];
    float xv[16] = {a0.x,a0.y,a0.z,a0.w, a1.x,a1.y,a1.z,a1.w,
                    a2.x,a2.y,a2.z,a2.w, a3.x,a3.y,a3.z,a3.w};
#pragma unroll
    for (int t = 0; t < 16; ++t) acc[t] += w * xv[t];
  }
  float bb = bp[tid];
#pragma unroll
  for (int t = 0; t < 16; ++t) {
    int idx = (n0 + t) * D + tid;
    x1[idx] = x[idx] + acc[t] + bb;
  }
}

// ---------------- gate: softmax(8), top-2, bucketing + slot index ----------------
__global__ void gate_kernel(const float* __restrict__ xn2, const float* __restrict__ wg,
                            float* __restrict__ psum, int* __restrict__ ecnt,
                            int* __restrict__ ltok, int* __restrict__ sidx,
                            float* __restrict__ gwn) {
  int lane = threadIdx.x;  // 64
  int n = blockIdx.x * 64 + lane;
  const float4* xr = (const float4*)(xn2 + (size_t)n * D);
  float lg[E];
#pragma unroll
  for (int e = 0; e < E; ++e) lg[e] = 0.f;
  for (int dq = 0; dq < 32; ++dq) {
    float4 xv = xr[dq];
    int d = dq * 4;
#pragma unroll
    for (int e = 0; e < E; ++e)
      lg[e] += xv.x * wg[d*E + e] + xv.y * wg[(d+1)*E + e]
             + xv.z * wg[(d+2)*E + e] + xv.w * wg[(d+3)*E + e];
  }
  float mx = lg[0];
#pragma unroll
  for (int e = 1; e < E; ++e) mx = fmaxf(mx, lg[e]);
  float p[E]; float s = 0.f;
#pragma unroll
  for (int e = 0; e < E; ++e) { p[e] = __expf(lg[e] - mx); s += p[e]; }
  float invs = 1.f / s;
#pragma unroll
  for (int e = 0; e < E; ++e) p[e] *= invs;
#pragma unroll
  for (int e = 0; e < E; ++e) {
    float ve = wave_sum(p[e]);
    if (lane == 0) atomicAdd(&psum[e], ve);
  }
  int i1 = 0; float p1 = p[0];
#pragma unroll
  for (int e = 1; e < E; ++e) if (p[e] > p1) { p1 = p[e]; i1 = e; }
  int i2 = (i1 == 0) ? 1 : 0; float p2 = p[i2];
#pragma unroll
  for (int e = 0; e < E; ++e) if (e != i1 && p[e] > p2) { p2 = p[e]; i2 = e; }
  float gden = 1.f / (p1 + p2);
  for (int kk = 0; kk < 2; ++kk) {
    int ei = kk ? i2 : i1;
    float g = (kk ? p2 : p1) * gden;
#pragma unroll
    for (int e = 0; e < E; ++e) {
      unsigned long long msk = __ballot(ei == e);
      if (msk == 0) continue;
      int cnt = __popcll(msk);
      int leader = __ffsll(msk) - 1;
      int base = 0;
      if (lane == leader) base = atomicAdd(&ecnt[e], cnt);
      base = __shfl(base, leader);
      if (ei == e) {
        int off = __popcll(msk & ((1ULL << lane) - 1ULL));
        int pos = base + off;
        ltok[e * N + pos] = n;
        sidx[n * 2 + kk] = e * N + pos;
        gwn[n * 2 + kk] = g;
      }
    }
  }
}

// ---------------- MFMA grouped expert FFN: 64 tokens x 1 expert, 4 waves ----------------
// wave owns 16 tokens end-to-end: h^T = mfma(w1T, x); gelu in-reg; o^T = mfma(w2T, p)
__global__ __launch_bounds__(256) void moe_mfma(
    const _Float16* __restrict__ xh, const _Float16* __restrict__ w1T,
    const float* __restrict__ b1, const _Float16* __restrict__ w2T,
    const float* __restrict__ b2, const int* __restrict__ ecnt,
    const int* __restrict__ ltok, float* __restrict__ eo) {
  int e = blockIdx.y;
  int cnt = ecnt[e];
  int t0 = blockIdx.x * 64;
  if (t0 >= cnt) return;
  __shared__ int toks[64];
  int tid = threadIdx.x;
  if (tid < 64)
    toks[tid] = (t0 + tid < cnt) ? ltok[e * N + t0 + tid] : -1;
  __syncthreads();
  int w = tid >> 6;          // wave 0..3
  int l = tid & 63;
  int lg = l >> 4, lr = l & 15;
  int slot = 16 * w + lr;    // token slot in [0,64)
  int tok = toks[slot];
  // x B-frags: B[d=16kd+4lg+i][t=lr] = xh[tok][16kd+4lg+i]
  const h4* xp = (const h4*)(xh + (size_t)(tok < 0 ? 0 : tok) * D + 4 * lg);
  h4 xf[8];
#pragma unroll
  for (int kd = 0; kd < 8; ++kd) xf[kd] = xp[kd * 4];
  // w1T A-frag (ft,kd): w1T[(16ft+lr)*D + 16kd+4lg]
  const h4* w1p = (const h4*)(w1T + (size_t)e * FF * D + (size_t)lr * D + 4 * lg);
  // w2T A-frag (dt,ft): w2T[(16dt+lr)*FF + 16ft+4lg]
  const h4* w2p = (const h4*)(w2T + (size_t)e * D * FF + (size_t)lr * FF + 4 * lg);
  f4 oacc[8];
#pragma unroll
  for (int dt = 0; dt < 8; ++dt) oacc[dt] = (f4){0.f,0.f,0.f,0.f};
  const float* b1e = b1 + e * FF;
#pragma unroll 2
  for (int ft = 0; ft < 32; ++ft) {
    f4 ha = {0.f,0.f,0.f,0.f};
#pragma unroll
    for (int kd = 0; kd < 8; ++kd)
      ha = MFMA16(w1p[ft * 512 + kd * 4], xf[kd], ha, 0, 0, 0);
    // h row f = 16ft + 4lg + i ; bias + exact gelu
    float4 bb = *(const float4*)&b1e[16 * ft + 4 * lg];
    h4 pf;
    {
      float z;
      z = ha.x + bb.x; pf.x = (_Float16)(0.5f * z * (1.f + erff(z * 0.70710678f)));
      z = ha.y + bb.y; pf.y = (_Float16)(0.5f * z * (1.f + erff(z * 0.70710678f)));
      z = ha.z + bb.z; pf.z = (_Float16)(0.5f * z * (1.f + erff(z * 0.70710678f)));
      z = ha.w + bb.w; pf.w = (_Float16)(0.5f * z * (1.f + erff(z * 0.70710678f)));
    }
#pragma unroll
    for (int dt = 0; dt < 8; ++dt)
      oacc[dt] = MFMA16(w2p[dt * 2048 + ft * 4], pf, oacc[dt], 0, 0, 0);
  }
  if (tok < 0) return;   // padded slot: nothing to store (exec-masked)
  float* eop = eo + ((size_t)(e * N + t0 + slot)) * 128;
  const float* b2e = b2 + e * D;
#pragma unroll
  for (int dt = 0; dt < 8; ++dt) {
    float4 bb = *(const float4*)&b2e[16 * dt + 4 * lg];
    float4 o4 = {oacc[dt].x + bb.x, oacc[dt].y + bb.y,
                 oacc[dt].z + bb.z, oacc[dt].w + bb.w};
    *(float4*)(eop + 16 * dt + 4 * lg) = o4;
  }
}

// ---------------- finalize: out = x1 + g0*eo[i0] + g1*eo[i1]; aux ----------------
__global__ void finalize_kernel(const float* __restrict__ x1, const float* __restrict__ eo,
                                const int* __restrict__ sidx, const float* __restrict__ gwn,
                                const float* __restrict__ psum, const int* __restrict__ ecnt,
                                float* __restrict__ out) {
  int idx = blockIdx.x * 256 + threadIdx.x;   // float4 index, N*D/4 total
  int n = idx >> 5, d4 = idx & 31;
  int i0 = sidx[2*n], i1 = sidx[2*n+1];
  float g0 = gwn[2*n], g1 = gwn[2*n+1];
  float4 a = ((const float4*)x1)[idx];
  float4 u = ((const float4*)eo)[(size_t)i0 * 32 + d4];
  float4 w = ((const float4*)eo)[(size_t)i1 * 32 + d4];
  float4 o = {a.x + g0*u.x + g1*w.x, a.y + g0*u.y + g1*w.y,
              a.z + g0*u.z + g1*w.z, a.w + g0*u.w + g1*w.w};
  ((float4*)out)[idx] = o;
  if (idx == 0) {
    float aux = 0.f;
    for (int e = 0; e < E; ++e)
      aux += ((float)ecnt[e] * (1.f / 16384.f)) * (psum[e] * (1.f / 8192.f));
    out[N * D] = 8.f * aux;
  }
}

extern "C" void kernel_launch(void* const* d_in, const int* in_sizes, int n_in,
                              void* d_out, int out_size, void* d_ws, size_t ws_size,
                              hipStream_t stream) {
  const float* x    = (const float*)d_in[0];
  const float* ln1g = (const float*)d_in[1];
  const float* ln1b = (const float*)d_in[2];
  const float* wq   = (const float*)d_in[3];
  const float* wk   = (const float*)d_in[4];
  const float* wv   = (const float*)d_in[5];
  const float* wp   = (const float*)d_in[6];
  const float* bp   = (const float*)d_in[7];
  const float* ln2g = (const float*)d_in[8];
  const float* ln2b = (const float*)d_in[9];
  const float* wg   = (const float*)d_in[10];
  const float* w1   = (const float*)d_in[11];
  const float* b1   = (const float*)d_in[12];
  const float* w2   = (const float*)d_in[13];
  const float* b2   = (const float*)d_in[14];
  float* out = (float*)d_out;
  float* ws = (float*)d_ws;
  const size_t M = 1u << 20;  // 1M floats
  // timeline-checked layout (floats):
  // [0,1M)    A   : xn -> attn-out
  // [1M,2M)   Bq  : x1
  // [2M,2.5M) qh (f16) -> xh (f16, after attn)   [2.5M,3M) kh   [3M,3.5M) vTh
  // [3.5M,12.5M) part ; eo reuses [3.5M,11.5M)
  // [12M,13M) xn2 (written after part is dead)
  // [13M,13.25M) w1T f16   [13.25M,13.5M) w2T f16
  // [13.5M,..) ltok/sidx/gwn/psum/ecnt
  float* A  = ws;
  float* Bq = ws + 1 * M;
  _Float16* qh  = (_Float16*)(ws + 2 * M);
  _Float16* xh  = (_Float16*)(ws + 2 * M);       // reuses qh region
  _Float16* kh  = (_Float16*)(ws + 2 * M + M / 2);
  _Float16* vTh = (_Float16*)(ws + 3 * M);
  float* part = ws + 3 * M + M / 2;
  float* eo   = part;
  float* xn2  = ws + 12 * M;
  _Float16* w1T = (_Float16*)(ws + 13 * M);
  _Float16* w2T = (_Float16*)(ws + 13 * M + M / 4);
  size_t G0 = 13 * M + M / 2;
  int*   ltok = (int*)(ws + G0);             // 65536 ints
  int*   sidx = (int*)(ws + G0 + 65536);     // 16384 ints
  float* gwn  = ws + G0 + 81920;             // 16384 floats
  float* psum = ws + G0 + 98304;             // 8
  int*   ecnt = (int*)(ws + G0 + 98312);     // 8

  hipMemsetAsync(psum, 0, 64, stream);       // psum + ecnt
  transpose_f16<<<dim3(FF/32, D/32, E), 256, 0, stream>>>(w1, w1T, D, FF);  // [D][FF]->[FF][D]
  transpose_f16<<<dim3(D/32, FF/32, E), 256, 0, stream>>>(w2, w2T, FF, D);  // [FF][D]->[D][FF]
  ln_kernel<<<N, 64, 0, stream>>>(x, ln1g, ln1b, A, nullptr);
  qkv_kernel<<<N / 16, 384, 0, stream>>>(A, wq, wk, wv, qh, kh, vTh);
  attn_mfma<<<dim3(32 * SPLITS, Bsz * H), 64, 0, stream>>>(qh, kh, vTh, part);
  attn_comb<<<NQ / 64, 64, 0, stream>>>(part, A);
  proj_kernel<<<N / 16, 128, 0, stream>>>(A, wp, bp, x, Bq);
  ln_kernel<<<N, 64, 0, stream>>>(Bq, ln2g, ln2b, xn2, xh);
  gate_kernel<<<N / 64, 64, 0, stream>>>(xn2, wg, psum, ecnt, ltok, sidx, gwn);
  moe_mfma<<<dim3(128, E), 256, 0, stream>>>(xh, w1T, b1, w2T, b2, ecnt, ltok, eo);
  finalize_kernel<<<(N * D / 4) / 256, 256, 0, stream>>>(Bq, eo, sidx, gwn, psum, ecnt, out);
}

// Round 5
// 192.430 us; speedup vs baseline: 2.0532x; 2.0532x over previous
//
#include <hip/hip_runtime.h>
#include <math.h>

#define Bsz 4
#define T 2048
#define D 128
#define H 8
#define HS 16
#define E 8
#define FF 512
#define N (Bsz*T)     // 8192
#define NQ (Bsz*H*T)  // 65536 query rows
#define EPS 1e-5f
#define SCALE 0.25f   // 1/sqrt(16)
#define SPLITS 8

typedef _Float16 h4 __attribute__((ext_vector_type(4)));
typedef _Float16 h2 __attribute__((ext_vector_type(2)));
typedef float f4 __attribute__((ext_vector_type(4)));
#define MFMA16 __builtin_amdgcn_mfma_f32_16x16x16f16

__device__ __forceinline__ float wave_sum(float v) {
#pragma unroll
  for (int off = 32; off >= 1; off >>= 1) v += __shfl_xor(v, off);
  return v;
}

// ---------------- LayerNorm: one wave per row of 128 (optional f16 copy) ----------------
__global__ void ln_kernel(const float* __restrict__ x, const float* __restrict__ g,
                          const float* __restrict__ b, float* __restrict__ out,
                          _Float16* __restrict__ outh) {
  int n = blockIdx.x;
  int tid = threadIdx.x;  // 64
  float2 v = ((const float2*)(x + n * D))[tid];
  float s  = wave_sum(v.x + v.y);
  float s2 = wave_sum(v.x * v.x + v.y * v.y);
  float m = s * (1.f / D);
  float var = s2 * (1.f / D) - m * m;
  float r = rsqrtf(var + EPS);
  float2 gg = ((const float2*)g)[tid];
  float2 bb = ((const float2*)b)[tid];
  float2 o;
  o.x = (v.x - m) * r * gg.x + bb.x;
  o.y = (v.y - m) * r * gg.y + bb.y;
  ((float2*)(out + n * D))[tid] = o;
  if (outh) {
    h2 hv = {(_Float16)o.x, (_Float16)o.y};
    ((h2*)(outh + n * D))[tid] = hv;
  }
}

// ---------------- weight packing: fragment-major tiles ----------------
// w1pk[(((e*32+ft)*8+kd)*64+l)*4+i] = w1[e][16kd+4lg+i][16ft+lr]
__global__ void pack_w1(const float* __restrict__ w1, _Float16* __restrict__ w1pk) {
  int ft = blockIdx.x, kd = blockIdx.y, e = blockIdx.z;
  int l = threadIdx.x, lg = l >> 4, lr = l & 15;
  const float* src = w1 + (size_t)e * D * FF;
  h4 v;
#pragma unroll
  for (int i = 0; i < 4; ++i)
    v[i] = (_Float16)src[(size_t)(16 * kd + 4 * lg + i) * FF + 16 * ft + lr];
  ((h4*)w1pk)[(((size_t)e * 32 + ft) * 8 + kd) * 64 + l] = v;
}
// w2pk[(((e*32+ft)*8+dt)*64+l)*4+i] = w2[e][16ft+4lg+i][16dt+lr]
__global__ void pack_w2(const float* __restrict__ w2, _Float16* __restrict__ w2pk) {
  int ft = blockIdx.x, dt = blockIdx.y, e = blockIdx.z;
  int l = threadIdx.x, lg = l >> 4, lr = l & 15;
  const float* src = w2 + (size_t)e * FF * D;
  h4 v;
#pragma unroll
  for (int i = 0; i < 4; ++i)
    v[i] = (_Float16)src[(size_t)(16 * ft + 4 * lg + i) * D + 16 * dt + lr];
  ((h4*)w2pk)[(((size_t)e * 32 + ft) * 8 + dt) * 64 + l] = v;
}

// ---------------- QKV: 16 tokens/block, 384 threads; f16 outputs ----------------
__global__ void qkv_kernel(const float* __restrict__ xn, const float* __restrict__ wq,
                           const float* __restrict__ wk, const float* __restrict__ wv,
                           _Float16* __restrict__ qh, _Float16* __restrict__ kh,
                           _Float16* __restrict__ vTh) {
  __shared__ float xs[D][20];
  int n0 = blockIdx.x * 16;
  int tid = threadIdx.x;
  for (int idx = tid; idx < 16 * D; idx += 384) {
    int t = idx >> 7, d = idx & 127;
    xs[d][t] = xn[(n0 + t) * D + d];
  }
  __syncthreads();
  int grp = tid / 128;        // 0=q 1=k 2=v (wave-uniform)
  int o = tid & 127;
  int h = o >> 4, e = o & 15;
  const float* w = (grp == 0 ? wq : (grp == 1 ? wk : wv)) + h * D * HS + e;
  float acc[16];
#pragma unroll
  for (int t = 0; t < 16; ++t) acc[t] = 0.f;
  for (int d = 0; d < D; ++d) {
    float wv_ = w[d * HS];
    float4 a0 = *(const float4*)&xs[d][0];
    float4 a1 = *(const float4*)&xs[d][4];
    float4 a2 = *(const float4*)&xs[d][8];
    float4 a3 = *(const float4*)&xs[d][12];
    float xv[16] = {a0.x,a0.y,a0.z,a0.w, a1.x,a1.y,a1.z,a1.w,
                    a2.x,a2.y,a2.z,a2.w, a3.x,a3.y,a3.z,a3.w};
#pragma unroll
    for (int t = 0; t < 16; ++t) acc[t] += wv_ * xv[t];
  }
  int b_ = n0 / T, t0 = n0 % T;
  if (grp == 0) {
    _Float16* dq = qh + ((size_t)(b_ * H + h) * T + t0) * 16 + e;
#pragma unroll
    for (int t = 0; t < 16; ++t) dq[t * 16] = (_Float16)(acc[t] * SCALE);
  } else if (grp == 1) {
    _Float16* dk = kh + ((size_t)(b_ * H + h) * T + t0) * 16 + e;
#pragma unroll
    for (int t = 0; t < 16; ++t) dk[t * 16] = (_Float16)acc[t];
  } else {
    _Float16* dv = vTh + ((size_t)(b_ * H + h) * 16 + e) * T + t0;
#pragma unroll
    for (int t = 0; t < 16; ++t) dv[t] = (_Float16)acc[t];
  }
}

// ---------------- MFMA flash attention partial ----------------
__global__ __launch_bounds__(64) void attn_mfma(
    const _Float16* __restrict__ q, const _Float16* __restrict__ k,
    const _Float16* __restrict__ vT, float* __restrict__ part) {
  int bh = blockIdx.y;
  int qt = blockIdx.x >> 3;     // 0..31 (64 queries)
  int s  = blockIdx.x & 7;      // split: keys [256s, 256s+256)
  int glo = 4 * s;
  int ghi = min(glo + 4, qt + 1);
  if (glo >= ghi) return;
  int l = threadIdx.x;
  int lg = l >> 4, lr = l & 15;
  int q0 = qt * 64;
  const h4* qp = (const h4*)(q + ((size_t)bh * T + q0 + lr) * 16 + 4 * lg);
  h4 qf[4];
#pragma unroll
  for (int nt = 0; nt < 4; ++nt) qf[nt] = qp[nt * 64];
  f4 o0 = {0.f,0.f,0.f,0.f}, o1 = o0, o2 = o0, o3 = o0;
  float m0 = -1e30f, m1 = -1e30f, m2 = -1e30f, m3 = -1e30f;
  float l0 = 0.f, l1 = 0.f, l2 = 0.f, l3 = 0.f;
  for (int g = glo; g < ghi; ++g) {
    int k0g = g * 64;
    const h4* kp = (const h4*)(k + ((size_t)bh * T + k0g + lr) * 16 + 4 * lg);
    h4 kf[4];
#pragma unroll
    for (int mt = 0; mt < 4; ++mt) kf[mt] = kp[mt * 64];
    const h4* vp = (const h4*)(vT + ((size_t)bh * 16 + lr) * T + k0g + 4 * lg);
    h4 vf[4];
#pragma unroll
    for (int mt = 0; mt < 4; ++mt) vf[mt] = vp[mt * 4];
    f4 z = {0.f,0.f,0.f,0.f};
    f4 sc[4][4];
#pragma unroll
    for (int mt = 0; mt < 4; ++mt)
#pragma unroll
      for (int nt = 0; nt < 4; ++nt)
        sc[mt][nt] = MFMA16(kf[mt], qf[nt], z, 0, 0, 0);
    if (g == qt) {  // diagonal tile: mask key > query
#pragma unroll
      for (int mt = 0; mt < 4; ++mt)
#pragma unroll
        for (int nt = 0; nt < 4; ++nt) {
          int kb = 16 * mt + 4 * lg, qb = 16 * nt + lr;
          if (kb + 0 > qb) sc[mt][nt].x = -1e30f;
          if (kb + 1 > qb) sc[mt][nt].y = -1e30f;
          if (kb + 2 > qb) sc[mt][nt].z = -1e30f;
          if (kb + 3 > qb) sc[mt][nt].w = -1e30f;
        }
    }
#define PROC(NT, M, L, O) do { \
    float tm = -1e30f; \
    _Pragma("unroll") for (int mt = 0; mt < 4; ++mt) { \
      f4 a = sc[mt][NT]; \
      tm = fmaxf(tm, fmaxf(fmaxf(a.x, a.y), fmaxf(a.z, a.w))); } \
    tm = fmaxf(tm, __shfl_xor(tm, 16)); \
    tm = fmaxf(tm, __shfl_xor(tm, 32)); \
    float mn = fmaxf(M, tm); \
    float c = __expf(M - mn); M = mn; L *= c; \
    O.x *= c; O.y *= c; O.z *= c; O.w *= c; \
    float sum = 0.f; h4 pf[4]; \
    _Pragma("unroll") for (int mt = 0; mt < 4; ++mt) { \
      f4 a = sc[mt][NT]; h4 p; float ex; \
      ex = __expf(a.x - mn); sum += ex; p.x = (_Float16)ex; \
      ex = __expf(a.y - mn); sum += ex; p.y = (_Float16)ex; \
      ex = __expf(a.z - mn); sum += ex; p.z = (_Float16)ex; \
      ex = __expf(a.w - mn); sum += ex; p.w = (_Float16)ex; \
      pf[mt] = p; } \
    sum += __shfl_xor(sum, 16); sum += __shfl_xor(sum, 32); L += sum; \
    _Pragma("unroll") for (int mt = 0; mt < 4; ++mt) \
      O = MFMA16(vf[mt], pf[mt], O, 0, 0, 0); \
  } while (0)
    PROC(0, m0, l0, o0);
    PROC(1, m1, l1, o1);
    PROC(2, m2, l2, o2);
    PROC(3, m3, l3, o3);
#undef PROC
  }
  float* pb = part + (size_t)s * 18 * NQ;
  int nbase = bh * T + q0 + lr;
#define WR(NT, M, L, O) do { int n = nbase + 16 * NT; \
    pb[(4 * lg + 0) * NQ + n] = O.x; pb[(4 * lg + 1) * NQ + n] = O.y; \
    pb[(4 * lg + 2) * NQ + n] = O.z; pb[(4 * lg + 3) * NQ + n] = O.w; \
    if (lg == 0) { pb[16 * NQ + n] = M; pb[17 * NQ + n] = L; } \
  } while (0)
  WR(0, m0, l0, o0);
  WR(1, m1, l1, o1);
  WR(2, m2, l2, o2);
  WR(3, m3, l3, o3);
#undef WR
}

// ---------------- attention combine: lane = one query row ----------------
__global__ void attn_comb(const float* __restrict__ part, float* __restrict__ ao) {
  int n = blockIdx.x * 64 + threadIdx.x;   // 0..NQ-1
  int t = n & (T - 1);
  int ns = (t >> 8) + 1;                   // splits with any keys <= t
  float m = -1e30f;
  for (int s = 0; s < ns; ++s)
    m = fmaxf(m, part[(s * 18 + 16) * NQ + n]);
  float acc[16];
#pragma unroll
  for (int e = 0; e < 16; ++e) acc[e] = 0.f;
  float L = 0.f;
  for (int s = 0; s < ns; ++s) {
    float w = __expf(part[(s * 18 + 16) * NQ + n] - m);
    L += w * part[(s * 18 + 17) * NQ + n];
#pragma unroll
    for (int e = 0; e < 16; ++e)
      acc[e] += w * part[(s * 18 + e) * NQ + n];
  }
  float inv = 1.f / L;
  int bh = n >> 11, b = bh >> 3, h = bh & 7;
  float* op = ao + ((size_t)(b * T + t) * D) + h * HS;
#pragma unroll
  for (int r = 0; r < 4; ++r) {
    float4 o4 = {acc[4*r]*inv, acc[4*r+1]*inv, acc[4*r+2]*inv, acc[4*r+3]*inv};
    ((float4*)op)[r] = o4;
  }
}

// ---------------- proj + bias + residual ----------------
__global__ void proj_kernel(const float* __restrict__ attn, const float* __restrict__ wp,
                            const float* __restrict__ bp, const float* __restrict__ x,
                            float* __restrict__ x1) {
  __shared__ float as_[D][20];
  int n0 = blockIdx.x * 16;
  int tid = threadIdx.x;  // 128
  for (int idx = tid; idx < 16 * D; idx += 128) {
    int t = idx >> 7, d = idx & 127;
    as_[d][t] = attn[(n0 + t) * D + d];
  }
  __syncthreads();
  float acc[16];
#pragma unroll
  for (int t = 0; t < 16; ++t) acc[t] = 0.f;
  for (int d = 0; d < D; ++d) {
    float w = wp[d * D + tid];
    float4 a0 = *(const float4*)&as_[d][0];
    float4 a1 = *(const float4*)&as_[d][4];
    float4 a2 = *(const float4*)&as_[d][8];
    float4 a3 = *(const float4*)&as_[d][12];
    float xv[16] = {a0.x,a0.y,a0.z,a0.w, a1.x,a1.y,a1.z,a1.w,
                    a2.x,a2.y,a2.z,a2.w, a3.x,a3.y,a3.z,a3.w};
#pragma unroll
    for (int t = 0; t < 16; ++t) acc[t] += w * xv[t];
  }
  float bb = bp[tid];
#pragma unroll
  for (int t = 0; t < 16; ++t) {
    int idx = (n0 + t) * D + tid;
    x1[idx] = x[idx] + acc[t] + bb;
  }
}

// ---------------- gate: softmax(8), top-2, bucketing + slot index ----------------
__global__ void gate_kernel(const float* __restrict__ xn2, const float* __restrict__ wg,
                            float* __restrict__ psum, int* __restrict__ ecnt,
                            int* __restrict__ ltok, int* __restrict__ sidx,
                            float* __restrict__ gwn) {
  int lane = threadIdx.x;  // 64
  int n = blockIdx.x * 64 + lane;
  const float4* xr = (const float4*)(xn2 + (size_t)n * D);
  float lg[E];
#pragma unroll
  for (int e = 0; e < E; ++e) lg[e] = 0.f;
  for (int dq = 0; dq < 32; ++dq) {
    float4 xv = xr[dq];
    int d = dq * 4;
#pragma unroll
    for (int e = 0; e < E; ++e)
      lg[e] += xv.x * wg[d*E + e] + xv.y * wg[(d+1)*E + e]
             + xv.z * wg[(d+2)*E + e] + xv.w * wg[(d+3)*E + e];
  }
  float mx = lg[0];
#pragma unroll
  for (int e = 1; e < E; ++e) mx = fmaxf(mx, lg[e]);
  float p[E]; float s = 0.f;
#pragma unroll
  for (int e = 0; e < E; ++e) { p[e] = __expf(lg[e] - mx); s += p[e]; }
  float invs = 1.f / s;
#pragma unroll
  for (int e = 0; e < E; ++e) p[e] *= invs;
#pragma unroll
  for (int e = 0; e < E; ++e) {
    float ve = wave_sum(p[e]);
    if (lane == 0) atomicAdd(&psum[e], ve);
  }
  int i1 = 0; float p1 = p[0];
#pragma unroll
  for (int e = 1; e < E; ++e) if (p[e] > p1) { p1 = p[e]; i1 = e; }
  int i2 = (i1 == 0) ? 1 : 0; float p2 = p[i2];
#pragma unroll
  for (int e = 0; e < E; ++e) if (e != i1 && p[e] > p2) { p2 = p[e]; i2 = e; }
  float gden = 1.f / (p1 + p2);
  for (int kk = 0; kk < 2; ++kk) {
    int ei = kk ? i2 : i1;
    float g = (kk ? p2 : p1) * gden;
#pragma unroll
    for (int e = 0; e < E; ++e) {
      unsigned long long msk = __ballot(ei == e);
      if (msk == 0) continue;
      int cnt = __popcll(msk);
      int leader = __ffsll(msk) - 1;
      int base = 0;
      if (lane == leader) base = atomicAdd(&ecnt[e], cnt);
      base = __shfl(base, leader);
      if (ei == e) {
        int off = __popcll(msk & ((1ULL << lane) - 1ULL));
        int pos = base + off;
        ltok[e * N + pos] = n;
        sidx[n * 2 + kk] = e * N + pos;
        gwn[n * 2 + kk] = g;
      }
    }
  }
}

// ---------------- MFMA grouped expert FFN: 32 tokens/block, FF split across wave pairs ----
// wave (tg, fh): 16 tokens (tg), ft in [16fh,16fh+16); partial oacc reduced via LDS.
__global__ __launch_bounds__(256) void moe_mfma(
    const _Float16* __restrict__ xh, const _Float16* __restrict__ w1pk,
    const float* __restrict__ b1, const _Float16* __restrict__ w2pk,
    const float* __restrict__ b2, const int* __restrict__ ecnt,
    const int* __restrict__ ltok, float* __restrict__ eo) {
  int e = blockIdx.y;
  int cnt = ecnt[e];
  int t0 = blockIdx.x * 32;
  if (t0 >= cnt) return;
  __shared__ int toks[32];
  __shared__ f4 red[2][8][64];
  int tid = threadIdx.x;
  if (tid < 32)
    toks[tid] = (t0 + tid < cnt) ? ltok[e * N + t0 + tid] : -1;
  __syncthreads();
  int w = tid >> 6;
  int l = tid & 63;
  int lg = l >> 4, lr = l & 15;
  int tg = w >> 1, fh = w & 1;
  int slot = 16 * tg + lr;
  int tok = toks[slot];
  const h4* xp = (const h4*)(xh + (size_t)(tok < 0 ? 0 : tok) * D + 4 * lg);
  h4 xf[8];
#pragma unroll
  for (int kd = 0; kd < 8; ++kd) xf[kd] = xp[kd * 4];
  f4 oacc[8];
#pragma unroll
  for (int dt = 0; dt < 8; ++dt) oacc[dt] = (f4){0.f,0.f,0.f,0.f};
  const float* b1e = b1 + e * FF;
  const h4* w1b = (const h4*)w1pk + ((size_t)e * 32 + 16 * fh) * 8 * 64 + l;
  const h4* w2b = (const h4*)w2pk + ((size_t)e * 32 + 16 * fh) * 8 * 64 + l;
#pragma unroll 2
  for (int ftl = 0; ftl < 16; ++ftl) {
    f4 ha = {0.f,0.f,0.f,0.f};
#pragma unroll
    for (int kd = 0; kd < 8; ++kd)
      ha = MFMA16(w1b[(ftl * 8 + kd) * 64], xf[kd], ha, 0, 0, 0);
    int ft = 16 * fh + ftl;
    float4 bb = *(const float4*)&b1e[16 * ft + 4 * lg];
    h4 pf;
    {
      float z;
      z = ha.x + bb.x; pf.x = (_Float16)(0.5f * z * (1.f + erff(z * 0.70710678f)));
      z = ha.y + bb.y; pf.y = (_Float16)(0.5f * z * (1.f + erff(z * 0.70710678f)));
      z = ha.z + bb.z; pf.z = (_Float16)(0.5f * z * (1.f + erff(z * 0.70710678f)));
      z = ha.w + bb.w; pf.w = (_Float16)(0.5f * z * (1.f + erff(z * 0.70710678f)));
    }
#pragma unroll
    for (int dt = 0; dt < 8; ++dt)
      oacc[dt] = MFMA16(w2b[(ftl * 8 + dt) * 64], pf, oacc[dt], 0, 0, 0);
  }
  if (fh == 1) {
#pragma unroll
    for (int dt = 0; dt < 8; ++dt) red[tg][dt][l] = oacc[dt];
  }
  __syncthreads();
  if (fh == 0 && tok >= 0) {
    const float* b2e = b2 + e * D;
    float* eop = eo + ((size_t)(e * N + t0 + slot)) * 128;
#pragma unroll
    for (int dt = 0; dt < 8; ++dt) {
      f4 r = red[tg][dt][l];
      float4 bb = *(const float4*)&b2e[16 * dt + 4 * lg];
      float4 o4 = {oacc[dt].x + r.x + bb.x, oacc[dt].y + r.y + bb.y,
                   oacc[dt].z + r.z + bb.z, oacc[dt].w + r.w + bb.w};
      *(float4*)(eop + 16 * dt + 4 * lg) = o4;
    }
  }
}

// ---------------- finalize: out = x1 + g0*eo[i0] + g1*eo[i1]; aux ----------------
__global__ void finalize_kernel(const float* __restrict__ x1, const float* __restrict__ eo,
                                const int* __restrict__ sidx, const float* __restrict__ gwn,
                                const float* __restrict__ psum, const int* __restrict__ ecnt,
                                float* __restrict__ out) {
  int idx = blockIdx.x * 256 + threadIdx.x;   // float4 index, N*D/4 total
  int n = idx >> 5, d4 = idx & 31;
  int i0 = sidx[2*n], i1 = sidx[2*n+1];
  float g0 = gwn[2*n], g1 = gwn[2*n+1];
  float4 a = ((const float4*)x1)[idx];
  float4 u = ((const float4*)eo)[(size_t)i0 * 32 + d4];
  float4 w = ((const float4*)eo)[(size_t)i1 * 32 + d4];
  float4 o = {a.x + g0*u.x + g1*w.x, a.y + g0*u.y + g1*w.y,
              a.z + g0*u.z + g1*w.z, a.w + g0*u.w + g1*w.w};
  ((float4*)out)[idx] = o;
  if (idx == 0) {
    float aux = 0.f;
    for (int e = 0; e < E; ++e)
      aux += ((float)ecnt[e] * (1.f / 16384.f)) * (psum[e] * (1.f / 8192.f));
    out[N * D] = 8.f * aux;
  }
}

extern "C" void kernel_launch(void* const* d_in, const int* in_sizes, int n_in,
                              void* d_out, int out_size, void* d_ws, size_t ws_size,
                              hipStream_t stream) {
  const float* x    = (const float*)d_in[0];
  const float* ln1g = (const float*)d_in[1];
  const float* ln1b = (const float*)d_in[2];
  const float* wq   = (const float*)d_in[3];
  const float* wk   = (const float*)d_in[4];
  const float* wv   = (const float*)d_in[5];
  const float* wp   = (const float*)d_in[6];
  const float* bp   = (const float*)d_in[7];
  const float* ln2g = (const float*)d_in[8];
  const float* ln2b = (const float*)d_in[9];
  const float* wg   = (const float*)d_in[10];
  const float* w1   = (const float*)d_in[11];
  const float* b1   = (const float*)d_in[12];
  const float* w2   = (const float*)d_in[13];
  const float* b2   = (const float*)d_in[14];
  float* out = (float*)d_out;
  float* ws = (float*)d_ws;
  const size_t M = 1u << 20;  // 1M floats
  // layout (floats):
  // [0,1M)    A   : xn -> attn-out
  // [1M,2M)   Bq  : x1
  // [2M,2.5M) qh (f16) -> xh (f16, after attn)   [2.5M,3M) kh   [3M,3.5M) vTh
  // [3.5M,12.5M) part ; eo reuses [3.5M,11.5M)
  // [12M,13M) xn2 (written after part is dead)
  // [13M,13.25M) w1pk f16   [13.25M,13.5M) w2pk f16
  // [13.5M,..) ltok/sidx/gwn/psum/ecnt
  float* A  = ws;
  float* Bq = ws + 1 * M;
  _Float16* qh  = (_Float16*)(ws + 2 * M);
  _Float16* xh  = (_Float16*)(ws + 2 * M);       // reuses qh region
  _Float16* kh  = (_Float16*)(ws + 2 * M + M / 2);
  _Float16* vTh = (_Float16*)(ws + 3 * M);
  float* part = ws + 3 * M + M / 2;
  float* eo   = part;
  float* xn2  = ws + 12 * M;
  _Float16* w1pk = (_Float16*)(ws + 13 * M);
  _Float16* w2pk = (_Float16*)(ws + 13 * M + M / 4);
  size_t G0 = 13 * M + M / 2;
  int*   ltok = (int*)(ws + G0);             // 65536 ints
  int*   sidx = (int*)(ws + G0 + 65536);     // 16384 ints
  float* gwn  = ws + G0 + 81920;             // 16384 floats
  float* psum = ws + G0 + 98304;             // 8
  int*   ecnt = (int*)(ws + G0 + 98312);     // 8

  hipMemsetAsync(psum, 0, 64, stream);       // psum + ecnt
  pack_w1<<<dim3(32, 8, E), 64, 0, stream>>>(w1, w1pk);
  pack_w2<<<dim3(32, 8, E), 64, 0, stream>>>(w2, w2pk);
  ln_kernel<<<N, 64, 0, stream>>>(x, ln1g, ln1b, A, nullptr);
  qkv_kernel<<<N / 16, 384, 0, stream>>>(A, wq, wk, wv, qh, kh, vTh);
  attn_mfma<<<dim3(32 * SPLITS, Bsz * H), 64, 0, stream>>>(qh, kh, vTh, part);
  attn_comb<<<NQ / 64, 64, 0, stream>>>(part, A);
  proj_kernel<<<N / 16, 128, 0, stream>>>(A, wp, bp, x, Bq);
  ln_kernel<<<N, 64, 0, stream>>>(Bq, ln2g, ln2b, xn2, xh);
  gate_kernel<<<N / 64, 64, 0, stream>>>(xn2, wg, psum, ecnt, ltok, sidx, gwn);
  moe_mfma<<<dim3(N / 32, E), 256, 0, stream>>>(xh, w1pk, b1, w2pk, b2, ecnt, ltok, eo);
  finalize_kernel<<<(N * D / 4) / 256, 256, 0, stream>>>(Bq, eo, sidx, gwn, psum, ecnt, out);
}

// Round 7
// 177.675 us; speedup vs baseline: 2.2237x; 1.0830x over previous
//
#include <hip/hip_runtime.h>
#include <math.h>

#define Bsz 4
#define T 2048
#define D 128
#define H 8
#define HS 16
#define E 8
#define FF 512
#define N (Bsz*T)     // 8192
#define NQ (Bsz*H*T)  // 65536 query rows
#define EPS 1e-5f
#define SCALE2 0.36067376f   // 0.25 * log2(e)
#define SPLITS 8

typedef _Float16 h4 __attribute__((ext_vector_type(4)));
typedef _Float16 h2 __attribute__((ext_vector_type(2)));
typedef float f4 __attribute__((ext_vector_type(4)));
#define MFMA16 __builtin_amdgcn_mfma_f32_16x16x16f16
#define EXP2(x) __builtin_amdgcn_exp2f(x)

__device__ __forceinline__ float wave_sum(float v) {
#pragma unroll
  for (int off = 32; off >= 1; off >>= 1) v += __shfl_xor(v, off);
  return v;
}

// ---------------- LayerNorm: one wave per row of 128; f32 and/or f16 out ----------------
__global__ void ln_kernel(const float* __restrict__ x, const float* __restrict__ g,
                          const float* __restrict__ b, float* __restrict__ out,
                          _Float16* __restrict__ outh) {
  int n = blockIdx.x;
  int tid = threadIdx.x;  // 64
  float2 v = ((const float2*)(x + n * D))[tid];
  float s  = wave_sum(v.x + v.y);
  float s2 = wave_sum(v.x * v.x + v.y * v.y);
  float m = s * (1.f / D);
  float var = s2 * (1.f / D) - m * m;
  float r = rsqrtf(var + EPS);
  float2 gg = ((const float2*)g)[tid];
  float2 bb = ((const float2*)b)[tid];
  float2 o;
  o.x = (v.x - m) * r * gg.x + bb.x;
  o.y = (v.y - m) * r * gg.y + bb.y;
  if (out) ((float2*)(out + n * D))[tid] = o;
  if (outh) {
    h2 hv = {(_Float16)o.x, (_Float16)o.y};
    ((h2*)(outh + n * D))[tid] = hv;
  }
}

// ---------------- weight packing: fragment-major tiles (MoE) ----------------
__global__ void pack_w1(const float* __restrict__ w1, _Float16* __restrict__ w1pk) {
  int ft = blockIdx.x, kd = blockIdx.y, e = blockIdx.z;
  int l = threadIdx.x, lg = l >> 4, lr = l & 15;
  const float* src = w1 + (size_t)e * D * FF;
  h4 v;
#pragma unroll
  for (int i = 0; i < 4; ++i)
    v[i] = (_Float16)src[(size_t)(16 * kd + 4 * lg + i) * FF + 16 * ft + lr];
  ((h4*)w1pk)[(((size_t)e * 32 + ft) * 8 + kd) * 64 + l] = v;
}
__global__ void pack_w2(const float* __restrict__ w2, _Float16* __restrict__ w2pk) {
  int ft = blockIdx.x, dt = blockIdx.y, e = blockIdx.z;
  int l = threadIdx.x, lg = l >> 4, lr = l & 15;
  const float* src = w2 + (size_t)e * FF * D;
  h4 v;
#pragma unroll
  for (int i = 0; i < 4; ++i)
    v[i] = (_Float16)src[(size_t)(16 * ft + 4 * lg + i) * D + 16 * dt + lr];
  ((h4*)w2pk)[(((size_t)e * 32 + ft) * 8 + dt) * 64 + l] = v;
}

// ---------------- QKV: scalar f32 math (gate-safe), f16 outputs ----------------
__global__ void qkv_kernel(const float* __restrict__ xn, const float* __restrict__ wq,
                           const float* __restrict__ wk, const float* __restrict__ wv,
                           _Float16* __restrict__ qh, _Float16* __restrict__ kh,
                           _Float16* __restrict__ vTh) {
  __shared__ float xs[D][20];
  int n0 = blockIdx.x * 16;
  int tid = threadIdx.x;
  for (int idx = tid; idx < 16 * D; idx += 384) {
    int t = idx >> 7, d = idx & 127;
    xs[d][t] = xn[(n0 + t) * D + d];
  }
  __syncthreads();
  int grp = tid / 128;        // 0=q 1=k 2=v (wave-uniform)
  int o = tid & 127;
  int h = o >> 4, e = o & 15;
  const float* w = (grp == 0 ? wq : (grp == 1 ? wk : wv)) + h * D * HS + e;
  float acc[16];
#pragma unroll
  for (int t = 0; t < 16; ++t) acc[t] = 0.f;
  for (int d = 0; d < D; ++d) {
    float wv_ = w[d * HS];
    float4 a0 = *(const float4*)&xs[d][0];
    float4 a1 = *(const float4*)&xs[d][4];
    float4 a2 = *(const float4*)&xs[d][8];
    float4 a3 = *(const float4*)&xs[d][12];
    float xv[16] = {a0.x,a0.y,a0.z,a0.w, a1.x,a1.y,a1.z,a1.w,
                    a2.x,a2.y,a2.z,a2.w, a3.x,a3.y,a3.z,a3.w};
#pragma unroll
    for (int t = 0; t < 16; ++t) acc[t] += wv_ * xv[t];
  }
  int b_ = n0 / T, t0 = n0 % T;
  if (grp == 0) {
    _Float16* dq = qh + ((size_t)(b_ * H + h) * T + t0) * 16 + e;
#pragma unroll
    for (int t = 0; t < 16; ++t) dq[t * 16] = (_Float16)(acc[t] * SCALE2);
  } else if (grp == 1) {
    _Float16* dk = kh + ((size_t)(b_ * H + h) * T + t0) * 16 + e;
#pragma unroll
    for (int t = 0; t < 16; ++t) dk[t * 16] = (_Float16)acc[t];
  } else {
    _Float16* dv = vTh + ((size_t)(b_ * H + h) * 16 + e) * T + t0;
#pragma unroll
    for (int t = 0; t < 16; ++t) dv[t] = (_Float16)acc[t];
  }
}

// ---------------- MFMA flash attention partial (no-max softmax, exp2, prefetch) ----------
// partial layout: part[(s*18 + i)*NQ + n]; i: 0..15 acc(hs), 16 L
__global__ __launch_bounds__(64) void attn_mfma(
    const _Float16* __restrict__ q, const _Float16* __restrict__ k,
    const _Float16* __restrict__ vT, float* __restrict__ part) {
  int bh = blockIdx.y;
  int qt = blockIdx.x >> 3;     // 0..31 (64 queries)
  int s  = blockIdx.x & 7;      // split: keys [256s, 256s+256)
  int glo = 4 * s;
  int ghi = min(glo + 4, qt + 1);
  if (glo >= ghi) return;
  int l = threadIdx.x;
  int lg = l >> 4, lr = l & 15;
  int q0 = qt * 64;
  const h4* qp = (const h4*)(q + ((size_t)bh * T + q0 + lr) * 16 + 4 * lg);
  h4 qf[4];
#pragma unroll
  for (int nt = 0; nt < 4; ++nt) qf[nt] = qp[nt * 64];
  f4 o0 = {0.f,0.f,0.f,0.f}, o1 = o0, o2 = o0, o3 = o0;
  float L0 = 0.f, L1 = 0.f, L2 = 0.f, L3 = 0.f;
  h4 kf[4], vf[4], kf2[4], vf2[4];
#define LOADKV(G, KK, VV) do { \
    int k0g = (G) * 64; \
    const h4* kp = (const h4*)(k + ((size_t)bh * T + k0g + lr) * 16 + 4 * lg); \
    _Pragma("unroll") for (int mt = 0; mt < 4; ++mt) KK[mt] = kp[mt * 64]; \
    const h4* vp = (const h4*)(vT + ((size_t)bh * 16 + lr) * T + k0g + 4 * lg); \
    _Pragma("unroll") for (int mt = 0; mt < 4; ++mt) VV[mt] = vp[mt * 4]; \
  } while (0)
  LOADKV(glo, kf, vf);
  for (int g = glo; g < ghi; ++g) {
    bool more = (g + 1 < ghi);
    if (more) LOADKV(g + 1, kf2, vf2);
    f4 z = {0.f,0.f,0.f,0.f};
    f4 sc[4][4];
#pragma unroll
    for (int mt = 0; mt < 4; ++mt)
#pragma unroll
      for (int nt = 0; nt < 4; ++nt)
        sc[mt][nt] = MFMA16(kf[mt], qf[nt], z, 0, 0, 0);
    if (g == qt) {  // diagonal tile: mask key > query
#pragma unroll
      for (int mt = 0; mt < 4; ++mt)
#pragma unroll
        for (int nt = 0; nt < 4; ++nt) {
          int kb = 16 * mt + 4 * lg, qb = 16 * nt + lr;
          if (kb + 0 > qb) sc[mt][nt].x = -1e30f;
          if (kb + 1 > qb) sc[mt][nt].y = -1e30f;
          if (kb + 2 > qb) sc[mt][nt].z = -1e30f;
          if (kb + 3 > qb) sc[mt][nt].w = -1e30f;
        }
    }
#define PROC(NT, L, O) do { \
    h4 pf[4]; \
    _Pragma("unroll") for (int mt = 0; mt < 4; ++mt) { \
      f4 a = sc[mt][NT]; h4 p; float ex; \
      ex = EXP2(a.x); L += ex; p.x = (_Float16)ex; \
      ex = EXP2(a.y); L += ex; p.y = (_Float16)ex; \
      ex = EXP2(a.z); L += ex; p.z = (_Float16)ex; \
      ex = EXP2(a.w); L += ex; p.w = (_Float16)ex; \
      pf[mt] = p; } \
    _Pragma("unroll") for (int mt = 0; mt < 4; ++mt) \
      O = MFMA16(vf[mt], pf[mt], O, 0, 0, 0); \
  } while (0)
    PROC(0, L0, o0);
    PROC(1, L1, o1);
    PROC(2, L2, o2);
    PROC(3, L3, o3);
#undef PROC
    if (more) {
#pragma unroll
      for (int mt = 0; mt < 4; ++mt) { kf[mt] = kf2[mt]; vf[mt] = vf2[mt]; }
    }
  }
#undef LOADKV
  // reduce L across lg groups (lanes lr, lr+16, lr+32, lr+48)
  L0 += __shfl_xor(L0, 16); L0 += __shfl_xor(L0, 32);
  L1 += __shfl_xor(L1, 16); L1 += __shfl_xor(L1, 32);
  L2 += __shfl_xor(L2, 16); L2 += __shfl_xor(L2, 32);
  L3 += __shfl_xor(L3, 16); L3 += __shfl_xor(L3, 32);
  float* pb = part + (size_t)s * 18 * NQ;
  int nbase = bh * T + q0 + lr;
#define WR(NT, L, O) do { int n = nbase + 16 * NT; \
    pb[(4 * lg + 0) * NQ + n] = O.x; pb[(4 * lg + 1) * NQ + n] = O.y; \
    pb[(4 * lg + 2) * NQ + n] = O.z; pb[(4 * lg + 3) * NQ + n] = O.w; \
    if (lg == 0) pb[16 * NQ + n] = L; \
  } while (0)
  WR(0, L0, o0);
  WR(1, L1, o1);
  WR(2, L2, o2);
  WR(3, L3, o3);
#undef WR
}

// ---------------- attention combine: plain sums (no max), f32 out ----------------
__global__ void attn_comb(const float* __restrict__ part, float* __restrict__ ao) {
  int n = blockIdx.x * 64 + threadIdx.x;   // 0..NQ-1
  int t = n & (T - 1);
  int ns = (t >> 8) + 1;                   // splits with any keys <= t
  float acc[16];
#pragma unroll
  for (int e = 0; e < 16; ++e) acc[e] = 0.f;
  float L = 0.f;
  for (int s = 0; s < ns; ++s) {
    const float* pb = part + (size_t)s * 18 * NQ;
    L += pb[16 * NQ + n];
#pragma unroll
    for (int e = 0; e < 16; ++e)
      acc[e] += pb[e * NQ + n];
  }
  float inv = 1.f / L;
  int bh = n >> 11, b = bh >> 3, h = bh & 7;
  float* op = ao + ((size_t)(b * T + t) * D) + h * HS;
#pragma unroll
  for (int r = 0; r < 4; ++r) {
    float4 o4 = {acc[4*r]*inv, acc[4*r+1]*inv, acc[4*r+2]*inv, acc[4*r+3]*inv};
    ((float4*)op)[r] = o4;
  }
}

// ---------------- proj + bias + residual: scalar f32 (gate-safe) ----------------
__global__ void proj_kernel(const float* __restrict__ attn, const float* __restrict__ wp,
                            const float* __restrict__ bp, const float* __restrict__ x,
                            float* __restrict__ x1) {
  __shared__ float as_[D][20];
  int n0 = blockIdx.x * 16;
  int tid = threadIdx.x;  // 128
  for (int idx = tid; idx < 16 * D; idx += 128) {
    int t = idx >> 7, d = idx & 127;
    as_[d][t] = attn[(n0 + t) * D + d];
  }
  __syncthreads();
  float acc[16];
#pragma unroll
  for (int t = 0; t < 16; ++t) acc[t] = 0.f;
  for (int d = 0; d < D; ++d) {
    float w = wp[d * D + tid];
    float4 a0 = *(const float4*)&as_[d][0];
    float4 a1 = *(const float4*)&as_[d][4];
    float4 a2 = *(const float4*)&as_[d][8];
    float4 a3 = *(const float4*)&as_[d][12];
    float xv[16] = {a0.x,a0.y,a0.z,a0.w, a1.x,a1.y,a1.z,a1.w,
                    a2.x,a2.y,a2.z,a2.w, a3.x,a3.y,a3.z,a3.w};
#pragma unroll
    for (int t = 0; t < 16; ++t) acc[t] += w * xv[t];
  }
  float bb = bp[tid];
#pragma unroll
  for (int t = 0; t < 16; ++t) {
    int idx = (n0 + t) * D + tid;
    x1[idx] = x[idx] + acc[t] + bb;
  }
}

// ---------------- gate: softmax(8), top-2, bucketing + slot index ----------------
__global__ void gate_kernel(const float* __restrict__ xn2, const float* __restrict__ wg,
                            float* __restrict__ psum, int* __restrict__ ecnt,
                            int* __restrict__ ltok, int* __restrict__ sidx,
                            float* __restrict__ gwn) {
  int lane = threadIdx.x;  // 64
  int n = blockIdx.x * 64 + lane;
  const float4* xr = (const float4*)(xn2 + (size_t)n * D);
  float lg[E];
#pragma unroll
  for (int e = 0; e < E; ++e) lg[e] = 0.f;
  for (int dq = 0; dq < 32; ++dq) {
    float4 xv = xr[dq];
    int d = dq * 4;
#pragma unroll
    for (int e = 0; e < E; ++e)
      lg[e] += xv.x * wg[d*E + e] + xv.y * wg[(d+1)*E + e]
             + xv.z * wg[(d+2)*E + e] + xv.w * wg[(d+3)*E + e];
  }
  float mx = lg[0];
#pragma unroll
  for (int e = 1; e < E; ++e) mx = fmaxf(mx, lg[e]);
  float p[E]; float s = 0.f;
#pragma unroll
  for (int e = 0; e < E; ++e) { p[e] = __expf(lg[e] - mx); s += p[e]; }
  float invs = 1.f / s;
#pragma unroll
  for (int e = 0; e < E; ++e) p[e] *= invs;
#pragma unroll
  for (int e = 0; e < E; ++e) {
    float ve = wave_sum(p[e]);
    if (lane == 0) atomicAdd(&psum[e], ve);
  }
  int i1 = 0; float p1 = p[0];
#pragma unroll
  for (int e = 1; e < E; ++e) if (p[e] > p1) { p1 = p[e]; i1 = e; }
  int i2 = (i1 == 0) ? 1 : 0; float p2 = p[i2];
#pragma unroll
  for (int e = 0; e < E; ++e) if (e != i1 && p[e] > p2) { p2 = p[e]; i2 = e; }
  float gden = 1.f / (p1 + p2);
  for (int kk = 0; kk < 2; ++kk) {
    int ei = kk ? i2 : i1;
    float g = (kk ? p2 : p1) * gden;
#pragma unroll
    for (int e = 0; e < E; ++e) {
      unsigned long long msk = __ballot(ei == e);
      if (msk == 0) continue;
      int cnt = __popcll(msk);
      int leader = __ffsll(msk) - 1;
      int base = 0;
      if (lane == leader) base = atomicAdd(&ecnt[e], cnt);
      base = __shfl(base, leader);
      if (ei == e) {
        int off = __popcll(msk & ((1ULL << lane) - 1ULL));
        int pos = base + off;
        ltok[e * N + pos] = n;
        sidx[n * 2 + kk] = e * N + pos;
        gwn[n * 2 + kk] = g;
      }
    }
  }
}

// ---------------- MFMA grouped expert FFN: 32 tokens/block, FF split across wave pairs ----
__global__ __launch_bounds__(256) void moe_mfma(
    const _Float16* __restrict__ xh, const _Float16* __restrict__ w1pk,
    const float* __restrict__ b1, const _Float16* __restrict__ w2pk,
    const float* __restrict__ b2, const int* __restrict__ ecnt,
    const int* __restrict__ ltok, float* __restrict__ eo) {
  int e = blockIdx.y;
  int cnt = ecnt[e];
  int t0 = blockIdx.x * 32;
  if (t0 >= cnt) return;
  __shared__ int toks[32];
  __shared__ f4 red[2][8][64];
  int tid = threadIdx.x;
  if (tid < 32)
    toks[tid] = (t0 + tid < cnt) ? ltok[e * N + t0 + tid] : -1;
  __syncthreads();
  int w = tid >> 6;
  int l = tid & 63;
  int lg = l >> 4, lr = l & 15;
  int tg = w >> 1, fh = w & 1;
  int slot = 16 * tg + lr;
  int tok = toks[slot];
  const h4* xp = (const h4*)(xh + (size_t)(tok < 0 ? 0 : tok) * D + 4 * lg);
  h4 xf[8];
#pragma unroll
  for (int kd = 0; kd < 8; ++kd) xf[kd] = xp[kd * 4];
  f4 oacc[8];
#pragma unroll
  for (int dt = 0; dt < 8; ++dt) oacc[dt] = (f4){0.f,0.f,0.f,0.f};
  const float* b1e = b1 + e * FF;
  const h4* w1b = (const h4*)w1pk + ((size_t)e * 32 + 16 * fh) * 8 * 64 + l;
  const h4* w2b = (const h4*)w2pk + ((size_t)e * 32 + 16 * fh) * 8 * 64 + l;
#pragma unroll 2
  for (int ftl = 0; ftl < 16; ++ftl) {
    f4 ha = {0.f,0.f,0.f,0.f};
#pragma unroll
    for (int kd = 0; kd < 8; ++kd)
      ha = MFMA16(w1b[(ftl * 8 + kd) * 64], xf[kd], ha, 0, 0, 0);
    int ft = 16 * fh + ftl;
    float4 bb = *(const float4*)&b1e[16 * ft + 4 * lg];
    h4 pf;
    {
      float z;
      z = ha.x + bb.x; pf.x = (_Float16)(0.5f * z * (1.f + erff(z * 0.70710678f)));
      z = ha.y + bb.y; pf.y = (_Float16)(0.5f * z * (1.f + erff(z * 0.70710678f)));
      z = ha.z + bb.z; pf.z = (_Float16)(0.5f * z * (1.f + erff(z * 0.70710678f)));
      z = ha.w + bb.w; pf.w = (_Float16)(0.5f * z * (1.f + erff(z * 0.70710678f)));
    }
#pragma unroll
    for (int dt = 0; dt < 8; ++dt)
      oacc[dt] = MFMA16(w2b[(ftl * 8 + dt) * 64], pf, oacc[dt], 0, 0, 0);
  }
  if (fh == 1) {
#pragma unroll
    for (int dt = 0; dt < 8; ++dt) red[tg][dt][l] = oacc[dt];
  }
  __syncthreads();
  if (fh == 0 && tok >= 0) {
    const float* b2e = b2 + e * D;
    float* eop = eo + ((size_t)(e * N + t0 + slot)) * 128;
#pragma unroll
    for (int dt = 0; dt < 8; ++dt) {
      f4 r = red[tg][dt][l];
      float4 bb = *(const float4*)&b2e[16 * dt + 4 * lg];
      float4 o4 = {oacc[dt].x + r.x + bb.x, oacc[dt].y + r.y + bb.y,
                   oacc[dt].z + r.z + bb.z, oacc[dt].w + r.w + bb.w};
      *(float4*)(eop + 16 * dt + 4 * lg) = o4;
    }
  }
}

// ---------------- finalize: out = x1 + g0*eo[i0] + g1*eo[i1]; aux ----------------
__global__ void finalize_kernel(const float* __restrict__ x1, const float* __restrict__ eo,
                                const int* __restrict__ sidx, const float* __restrict__ gwn,
                                const float* __restrict__ psum, const int* __restrict__ ecnt,
                                float* __restrict__ out) {
  int idx = blockIdx.x * 256 + threadIdx.x;   // float4 index, N*D/4 total
  int n = idx >> 5, d4 = idx & 31;
  int i0 = sidx[2*n], i1 = sidx[2*n+1];
  float g0 = gwn[2*n], g1 = gwn[2*n+1];
  float4 a = ((const float4*)x1)[idx];
  float4 u = ((const float4*)eo)[(size_t)i0 * 32 + d4];
  float4 w = ((const float4*)eo)[(size_t)i1 * 32 + d4];
  float4 o = {a.x + g0*u.x + g1*w.x, a.y + g0*u.y + g1*w.y,
              a.z + g0*u.z + g1*w.z, a.w + g0*u.w + g1*w.w};
  ((float4*)out)[idx] = o;
  if (idx == 0) {
    float aux = 0.f;
    for (int e = 0; e < E; ++e)
      aux += ((float)ecnt[e] * (1.f / 16384.f)) * (psum[e] * (1.f / 8192.f));
    out[N * D] = 8.f * aux;
  }
}

extern "C" void kernel_launch(void* const* d_in, const int* in_sizes, int n_in,
                              void* d_out, int out_size, void* d_ws, size_t ws_size,
                              hipStream_t stream) {
  const float* x    = (const float*)d_in[0];
  const float* ln1g = (const float*)d_in[1];
  const float* ln1b = (const float*)d_in[2];
  const float* wq   = (const float*)d_in[3];
  const float* wk   = (const float*)d_in[4];
  const float* wv   = (const float*)d_in[5];
  const float* wp   = (const float*)d_in[6];
  const float* bp   = (const float*)d_in[7];
  const float* ln2g = (const float*)d_in[8];
  const float* ln2b = (const float*)d_in[9];
  const float* wg   = (const float*)d_in[10];
  const float* w1   = (const float*)d_in[11];
  const float* b1   = (const float*)d_in[12];
  const float* w2   = (const float*)d_in[13];
  const float* b2   = (const float*)d_in[14];
  float* out = (float*)d_out;
  float* ws = (float*)d_ws;
  const size_t M = 1u << 20;  // 1M floats
  // layout (floats) — identical timeline to round 5 (passed):
  // [0,1M)    A   : xn -> attn-out (f32)
  // [1M,2M)   Bq  : x1 (f32)
  // [2M,2.5M) qh f16 -> xh f16 (moe in)  [2.5M,3M) kh  [3M,3.5M) vTh
  // [3.5M,~12.94M) part ; eo reuses [3.5M,11.5M)
  // [12M,13M) xn2 f32 (written after part dead)
  // [13M,13.25M) w1pk  [13.25M,13.5M) w2pk
  // [13.5M,..) ltok/sidx/gwn/psum/ecnt
  float* A  = ws;
  float* Bq = ws + 1 * M;
  _Float16* qh  = (_Float16*)(ws + 2 * M);
  _Float16* xh  = (_Float16*)(ws + 2 * M);       // reuses qh region
  _Float16* kh  = (_Float16*)(ws + 2 * M + M / 2);
  _Float16* vTh = (_Float16*)(ws + 3 * M);
  float* part = ws + 3 * M + M / 2;
  float* eo   = part;
  float* xn2  = ws + 12 * M;
  _Float16* w1pk = (_Float16*)(ws + 13 * M);
  _Float16* w2pk = (_Float16*)(ws + 13 * M + M / 4);
  size_t G0 = 13 * M + M / 2;
  int*   ltok = (int*)(ws + G0);             // 65536 ints
  int*   sidx = (int*)(ws + G0 + 65536);     // 16384 ints
  float* gwn  = ws + G0 + 81920;             // 16384 floats
  float* psum = ws + G0 + 98304;             // 8
  int*   ecnt = (int*)(ws + G0 + 98312);     // 8

  hipMemsetAsync(psum, 0, 64, stream);       // psum + ecnt
  pack_w1<<<dim3(32, 8, E), 64, 0, stream>>>(w1, w1pk);
  pack_w2<<<dim3(32, 8, E), 64, 0, stream>>>(w2, w2pk);
  ln_kernel<<<N, 64, 0, stream>>>(x, ln1g, ln1b, A, nullptr);
  qkv_kernel<<<N / 16, 384, 0, stream>>>(A, wq, wk, wv, qh, kh, vTh);
  attn_mfma<<<dim3(32 * SPLITS, Bsz * H), 64, 0, stream>>>(qh, kh, vTh, part);
  attn_comb<<<NQ / 64, 64, 0, stream>>>(part, A);
  proj_kernel<<<N / 16, 128, 0, stream>>>(A, wp, bp, x, Bq);
  ln_kernel<<<N, 64, 0, stream>>>(Bq, ln2g, ln2b, xn2, xh);
  gate_kernel<<<N / 64, 64, 0, stream>>>(xn2, wg, psum, ecnt, ltok, sidx, gwn);
  moe_mfma<<<dim3(N / 32, E), 256, 0, stream>>>(xh, w1pk, b1, w2pk, b2, ecnt, ltok, eo);
  finalize_kernel<<<(N * D / 4) / 256, 256, 0, stream>>>(Bq, eo, sidx, gwn, psum, ecnt, out);
}

// Round 8
// 147.274 us; speedup vs baseline: 2.6828x; 1.2064x over previous
//
#include <hip/hip_runtime.h>
#include <math.h>

#define Bsz 4
#define T 2048
#define D 128
#define H 8
#define HS 16
#define E 8
#define FF 512
#define N (Bsz*T)     // 8192
#define NQ (Bsz*H*T)  // 65536 query rows
#define EPS 1e-5f
#define SCALE2 0.36067376f   // 0.25 * log2(e)
#define SPLITS 8

typedef _Float16 h4 __attribute__((ext_vector_type(4)));
typedef _Float16 h2 __attribute__((ext_vector_type(2)));
typedef float f4 __attribute__((ext_vector_type(4)));
#define MFMA16 __builtin_amdgcn_mfma_f32_16x16x16f16
#define EXP2(x) __builtin_amdgcn_exp2f(x)

__device__ __forceinline__ float wave_sum(float v) {
#pragma unroll
  for (int off = 32; off >= 1; off >>= 1) v += __shfl_xor(v, off);
  return v;
}

// ---------------- LayerNorm: one wave per row of 128; f32 and/or f16 out ----------------
__global__ void ln_kernel(const float* __restrict__ x, const float* __restrict__ g,
                          const float* __restrict__ b, float* __restrict__ out,
                          _Float16* __restrict__ outh) {
  int n = blockIdx.x;
  int tid = threadIdx.x;  // 64
  float2 v = ((const float2*)(x + n * D))[tid];
  float s  = wave_sum(v.x + v.y);
  float s2 = wave_sum(v.x * v.x + v.y * v.y);
  float m = s * (1.f / D);
  float var = s2 * (1.f / D) - m * m;
  float r = rsqrtf(var + EPS);
  float2 gg = ((const float2*)g)[tid];
  float2 bb = ((const float2*)b)[tid];
  float2 o;
  o.x = (v.x - m) * r * gg.x + bb.x;
  o.y = (v.y - m) * r * gg.y + bb.y;
  if (out) ((float2*)(out + n * D))[tid] = o;
  if (outh) {
    h2 hv = {(_Float16)o.x, (_Float16)o.y};
    ((h2*)(outh + n * D))[tid] = hv;
  }
}

// ---------------- weight packing: fragment-major tiles (MoE) ----------------
__global__ void pack_w1(const float* __restrict__ w1, _Float16* __restrict__ w1pk) {
  int ft = blockIdx.x, kd = blockIdx.y, e = blockIdx.z;
  int l = threadIdx.x, lg = l >> 4, lr = l & 15;
  const float* src = w1 + (size_t)e * D * FF;
  h4 v;
#pragma unroll
  for (int i = 0; i < 4; ++i)
    v[i] = (_Float16)src[(size_t)(16 * kd + 4 * lg + i) * FF + 16 * ft + lr];
  ((h4*)w1pk)[(((size_t)e * 32 + ft) * 8 + kd) * 64 + l] = v;
}
__global__ void pack_w2(const float* __restrict__ w2, _Float16* __restrict__ w2pk) {
  int ft = blockIdx.x, dt = blockIdx.y, e = blockIdx.z;
  int l = threadIdx.x, lg = l >> 4, lr = l & 15;
  const float* src = w2 + (size_t)e * FF * D;
  h4 v;
#pragma unroll
  for (int i = 0; i < 4; ++i)
    v[i] = (_Float16)src[(size_t)(16 * ft + 4 * lg + i) * D + 16 * dt + lr];
  ((h4*)w2pk)[(((size_t)e * 32 + ft) * 8 + dt) * 64 + l] = v;
}

// ---------------- QKV: scalar f32 math (gate-safe), f16 outputs ----------------
__global__ void qkv_kernel(const float* __restrict__ xn, const float* __restrict__ wq,
                           const float* __restrict__ wk, const float* __restrict__ wv,
                           _Float16* __restrict__ qh, _Float16* __restrict__ kh,
                           _Float16* __restrict__ vTh) {
  __shared__ float xs[D][20];
  int n0 = blockIdx.x * 16;
  int tid = threadIdx.x;
  for (int idx = tid; idx < 16 * D; idx += 384) {
    int t = idx >> 7, d = idx & 127;
    xs[d][t] = xn[(n0 + t) * D + d];
  }
  __syncthreads();
  int grp = tid / 128;        // 0=q 1=k 2=v (wave-uniform)
  int o = tid & 127;
  int h = o >> 4, e = o & 15;
  const float* w = (grp == 0 ? wq : (grp == 1 ? wk : wv)) + h * D * HS + e;
  float acc[16];
#pragma unroll
  for (int t = 0; t < 16; ++t) acc[t] = 0.f;
  for (int d = 0; d < D; ++d) {
    float wv_ = w[d * HS];
    float4 a0 = *(const float4*)&xs[d][0];
    float4 a1 = *(const float4*)&xs[d][4];
    float4 a2 = *(const float4*)&xs[d][8];
    float4 a3 = *(const float4*)&xs[d][12];
    float xv[16] = {a0.x,a0.y,a0.z,a0.w, a1.x,a1.y,a1.z,a1.w,
                    a2.x,a2.y,a2.z,a2.w, a3.x,a3.y,a3.z,a3.w};
#pragma unroll
    for (int t = 0; t < 16; ++t) acc[t] += wv_ * xv[t];
  }
  int b_ = n0 / T, t0 = n0 % T;
  if (grp == 0) {
    _Float16* dq = qh + ((size_t)(b_ * H + h) * T + t0) * 16 + e;
#pragma unroll
    for (int t = 0; t < 16; ++t) dq[t * 16] = (_Float16)(acc[t] * SCALE2);
  } else if (grp == 1) {
    _Float16* dk = kh + ((size_t)(b_ * H + h) * T + t0) * 16 + e;
#pragma unroll
    for (int t = 0; t < 16; ++t) dk[t * 16] = (_Float16)acc[t];
  } else {
    _Float16* dv = vTh + ((size_t)(b_ * H + h) * 16 + e) * T + t0;
#pragma unroll
    for (int t = 0; t < 16; ++t) dv[t] = (_Float16)acc[t];
  }
}

// ---------------- MFMA flash attention partial (no-max softmax, exp2, prefetch) ----------
// partial layout: part[(s*18 + i)*NQ + n]; i: 0..15 acc(hs), 16 L
__global__ __launch_bounds__(64) void attn_mfma(
    const _Float16* __restrict__ q, const _Float16* __restrict__ k,
    const _Float16* __restrict__ vT, float* __restrict__ part) {
  int bh = blockIdx.y;
  int qt = blockIdx.x >> 3;     // 0..31 (64 queries)
  int s  = blockIdx.x & 7;      // split: keys [256s, 256s+256)
  int glo = 4 * s;
  int ghi = min(glo + 4, qt + 1);
  if (glo >= ghi) return;
  int l = threadIdx.x;
  int lg = l >> 4, lr = l & 15;
  int q0 = qt * 64;
  const h4* qp = (const h4*)(q + ((size_t)bh * T + q0 + lr) * 16 + 4 * lg);
  h4 qf[4];
#pragma unroll
  for (int nt = 0; nt < 4; ++nt) qf[nt] = qp[nt * 64];
  f4 o0 = {0.f,0.f,0.f,0.f}, o1 = o0, o2 = o0, o3 = o0;
  float L0 = 0.f, L1 = 0.f, L2 = 0.f, L3 = 0.f;
  h4 kf[4], vf[4], kf2[4], vf2[4];
#define LOADKV(G, KK, VV) do { \
    int k0g = (G) * 64; \
    const h4* kp = (const h4*)(k + ((size_t)bh * T + k0g + lr) * 16 + 4 * lg); \
    _Pragma("unroll") for (int mt = 0; mt < 4; ++mt) KK[mt] = kp[mt * 64]; \
    const h4* vp = (const h4*)(vT + ((size_t)bh * 16 + lr) * T + k0g + 4 * lg); \
    _Pragma("unroll") for (int mt = 0; mt < 4; ++mt) VV[mt] = vp[mt * 4]; \
  } while (0)
  LOADKV(glo, kf, vf);
  for (int g = glo; g < ghi; ++g) {
    bool more = (g + 1 < ghi);
    if (more) LOADKV(g + 1, kf2, vf2);
    f4 z = {0.f,0.f,0.f,0.f};
    f4 sc[4][4];
#pragma unroll
    for (int mt = 0; mt < 4; ++mt)
#pragma unroll
      for (int nt = 0; nt < 4; ++nt)
        sc[mt][nt] = MFMA16(kf[mt], qf[nt], z, 0, 0, 0);
    if (g == qt) {  // diagonal tile: mask key > query
#pragma unroll
      for (int mt = 0; mt < 4; ++mt)
#pragma unroll
        for (int nt = 0; nt < 4; ++nt) {
          int kb = 16 * mt + 4 * lg, qb = 16 * nt + lr;
          if (kb + 0 > qb) sc[mt][nt].x = -1e30f;
          if (kb + 1 > qb) sc[mt][nt].y = -1e30f;
          if (kb + 2 > qb) sc[mt][nt].z = -1e30f;
          if (kb + 3 > qb) sc[mt][nt].w = -1e30f;
        }
    }
#define PROC(NT, L, O) do { \
    h4 pf[4]; \
    _Pragma("unroll") for (int mt = 0; mt < 4; ++mt) { \
      f4 a = sc[mt][NT]; h4 p; float ex; \
      ex = EXP2(a.x); L += ex; p.x = (_Float16)ex; \
      ex = EXP2(a.y); L += ex; p.y = (_Float16)ex; \
      ex = EXP2(a.z); L += ex; p.z = (_Float16)ex; \
      ex = EXP2(a.w); L += ex; p.w = (_Float16)ex; \
      pf[mt] = p; } \
    _Pragma("unroll") for (int mt = 0; mt < 4; ++mt) \
      O = MFMA16(vf[mt], pf[mt], O, 0, 0, 0); \
  } while (0)
    PROC(0, L0, o0);
    PROC(1, L1, o1);
    PROC(2, L2, o2);
    PROC(3, L3, o3);
#undef PROC
    if (more) {
#pragma unroll
      for (int mt = 0; mt < 4; ++mt) { kf[mt] = kf2[mt]; vf[mt] = vf2[mt]; }
    }
  }
#undef LOADKV
  // reduce L across lg groups (lanes lr, lr+16, lr+32, lr+48)
  L0 += __shfl_xor(L0, 16); L0 += __shfl_xor(L0, 32);
  L1 += __shfl_xor(L1, 16); L1 += __shfl_xor(L1, 32);
  L2 += __shfl_xor(L2, 16); L2 += __shfl_xor(L2, 32);
  L3 += __shfl_xor(L3, 16); L3 += __shfl_xor(L3, 32);
  float* pb = part + (size_t)s * 18 * NQ;
  int nbase = bh * T + q0 + lr;
#define WR(NT, L, O) do { int n = nbase + 16 * NT; \
    pb[(4 * lg + 0) * NQ + n] = O.x; pb[(4 * lg + 1) * NQ + n] = O.y; \
    pb[(4 * lg + 2) * NQ + n] = O.z; pb[(4 * lg + 3) * NQ + n] = O.w; \
    if (lg == 0) pb[16 * NQ + n] = L; \
  } while (0)
  WR(0, L0, o0);
  WR(1, L1, o1);
  WR(2, L2, o2);
  WR(3, L3, o3);
#undef WR
}

// ---------------- attention combine: plain sums (no max), f32 out ----------------
__global__ void attn_comb(const float* __restrict__ part, float* __restrict__ ao) {
  int n = blockIdx.x * 64 + threadIdx.x;   // 0..NQ-1
  int t = n & (T - 1);
  int ns = (t >> 8) + 1;                   // splits with any keys <= t
  float acc[16];
#pragma unroll
  for (int e = 0; e < 16; ++e) acc[e] = 0.f;
  float L = 0.f;
  for (int s = 0; s < ns; ++s) {
    const float* pb = part + (size_t)s * 18 * NQ;
    L += pb[16 * NQ + n];
#pragma unroll
    for (int e = 0; e < 16; ++e)
      acc[e] += pb[e * NQ + n];
  }
  float inv = 1.f / L;
  int bh = n >> 11, b = bh >> 3, h = bh & 7;
  float* op = ao + ((size_t)(b * T + t) * D) + h * HS;
#pragma unroll
  for (int r = 0; r < 4; ++r) {
    float4 o4 = {acc[4*r]*inv, acc[4*r+1]*inv, acc[4*r+2]*inv, acc[4*r+3]*inv};
    ((float4*)op)[r] = o4;
  }
}

// ---------------- proj + bias + residual: scalar f32 (gate-safe) ----------------
__global__ void proj_kernel(const float* __restrict__ attn, const float* __restrict__ wp,
                            const float* __restrict__ bp, const float* __restrict__ x,
                            float* __restrict__ x1) {
  __shared__ float as_[D][20];
  int n0 = blockIdx.x * 16;
  int tid = threadIdx.x;  // 128
  for (int idx = tid; idx < 16 * D; idx += 128) {
    int t = idx >> 7, d = idx & 127;
    as_[d][t] = attn[(n0 + t) * D + d];
  }
  __syncthreads();
  float acc[16];
#pragma unroll
  for (int t = 0; t < 16; ++t) acc[t] = 0.f;
  for (int d = 0; d < D; ++d) {
    float w = wp[d * D + tid];
    float4 a0 = *(const float4*)&as_[d][0];
    float4 a1 = *(const float4*)&as_[d][4];
    float4 a2 = *(const float4*)&as_[d][8];
    float4 a3 = *(const float4*)&as_[d][12];
    float xv[16] = {a0.x,a0.y,a0.z,a0.w, a1.x,a1.y,a1.z,a1.w,
                    a2.x,a2.y,a2.z,a2.w, a3.x,a3.y,a3.z,a3.w};
#pragma unroll
    for (int t = 0; t < 16; ++t) acc[t] += w * xv[t];
  }
  float bb = bp[tid];
#pragma unroll
  for (int t = 0; t < 16; ++t) {
    int idx = (n0 + t) * D + tid;
    x1[idx] = x[idx] + acc[t] + bb;
  }
}

// ---------------- gate phase 1: logits/softmax/top-2, wave histograms, ranks ----------------
__global__ void gate_part(const float* __restrict__ xn2, const float* __restrict__ wg,
                          int* __restrict__ wcnt, float* __restrict__ wpsum,
                          int4* __restrict__ tokinfo, float2* __restrict__ gws) {
  int lane = threadIdx.x;  // 64
  int blk = blockIdx.x;
  int n = blk * 64 + lane;
  const float4* xr = (const float4*)(xn2 + (size_t)n * D);
  float lg[E];
#pragma unroll
  for (int e = 0; e < E; ++e) lg[e] = 0.f;
  for (int dq = 0; dq < 32; ++dq) {
    float4 xv = xr[dq];
    int d = dq * 4;
#pragma unroll
    for (int e = 0; e < E; ++e)
      lg[e] += xv.x * wg[d*E + e] + xv.y * wg[(d+1)*E + e]
             + xv.z * wg[(d+2)*E + e] + xv.w * wg[(d+3)*E + e];
  }
  float mx = lg[0];
#pragma unroll
  for (int e = 1; e < E; ++e) mx = fmaxf(mx, lg[e]);
  float p[E]; float s = 0.f;
#pragma unroll
  for (int e = 0; e < E; ++e) { p[e] = __expf(lg[e] - mx); s += p[e]; }
  float invs = 1.f / s;
#pragma unroll
  for (int e = 0; e < E; ++e) p[e] *= invs;
#pragma unroll
  for (int e = 0; e < E; ++e) {
    float ve = wave_sum(p[e]);
    if (lane == 0) wpsum[blk * E + e] = ve;
  }
  int i1 = 0; float p1 = p[0];
#pragma unroll
  for (int e = 1; e < E; ++e) if (p[e] > p1) { p1 = p[e]; i1 = e; }
  int i2 = (i1 == 0) ? 1 : 0; float p2 = p[i2];
#pragma unroll
  for (int e = 0; e < E; ++e) if (e != i1 && p[e] > p2) { p2 = p[e]; i2 = e; }
  float gden = 1.f / (p1 + p2);
  unsigned long long lt = (1ULL << lane) - 1ULL;
  int woff0 = 0, woff1 = 0;
  int c0[E], ctot[E];
#pragma unroll
  for (int e = 0; e < E; ++e) {
    unsigned long long m0 = __ballot(i1 == e);
    c0[e] = __popcll(m0);
    if (i1 == e) woff0 = __popcll(m0 & lt);
  }
#pragma unroll
  for (int e = 0; e < E; ++e) {
    unsigned long long m1 = __ballot(i2 == e);
    if (i2 == e) woff1 = c0[e] + __popcll(m1 & lt);
    ctot[e] = c0[e] + __popcll(m1);
  }
  if (lane == 0) {
#pragma unroll
    for (int e = 0; e < E; ++e) wcnt[blk * E + e] = ctot[e];
  }
  tokinfo[n] = make_int4(i1, woff0, i2, woff1);
  gws[n] = make_float2(p1 * gden, p2 * gden);
}

// ---------------- gate phase 2: scan wave histograms -> bases, ecnt, psum ----------------
__global__ void gate_scan(const int* __restrict__ wcnt, const float* __restrict__ wpsum,
                          int* __restrict__ wbase, int* __restrict__ ecnt,
                          float* __restrict__ psum) {
  __shared__ int sc[128 * E];
  __shared__ float sp[128 * E];
  int tid = threadIdx.x;  // 64
  for (int i = tid; i < 128 * E; i += 64) { sc[i] = wcnt[i]; sp[i] = wpsum[i]; }
  __syncthreads();
  if (tid < E) {
    int run = 0;
    for (int b = 0; b < 128; ++b) { wbase[b * E + tid] = run; run += sc[b * E + tid]; }
    ecnt[tid] = run;
  } else if (tid >= 16 && tid < 16 + E) {
    int e = tid - 16;
    float sum = 0.f;
    for (int b = 0; b < 128; ++b) sum += sp[b * E + e];
    psum[e] = sum;
  }
}

// ---------------- gate phase 3: scatter tokens into expert buckets ----------------
__global__ void gate_scatter(const int4* __restrict__ tokinfo, const float2* __restrict__ gws,
                             const int* __restrict__ wbase,
                             int* __restrict__ ltok, int* __restrict__ sidx,
                             float* __restrict__ gwn) {
  int lane = threadIdx.x;  // 64
  int blk = blockIdx.x;
  int n = blk * 64 + lane;
  int4 ti = tokinfo[n];
  float2 g = gws[n];
  int pos0 = wbase[blk * E + ti.x] + ti.y;
  int pos1 = wbase[blk * E + ti.z] + ti.w;
  ltok[ti.x * N + pos0] = n;
  ltok[ti.z * N + pos1] = n;
  sidx[2 * n]     = ti.x * N + pos0;
  sidx[2 * n + 1] = ti.z * N + pos1;
  gwn[2 * n]     = g.x;
  gwn[2 * n + 1] = g.y;
}

// ---------------- MFMA grouped expert FFN: 32 tokens/block, FF split across wave pairs ----
__global__ __launch_bounds__(256) void moe_mfma(
    const _Float16* __restrict__ xh, const _Float16* __restrict__ w1pk,
    const float* __restrict__ b1, const _Float16* __restrict__ w2pk,
    const float* __restrict__ b2, const int* __restrict__ ecnt,
    const int* __restrict__ ltok, float* __restrict__ eo) {
  int e = blockIdx.y;
  int cnt = ecnt[e];
  int t0 = blockIdx.x * 32;
  if (t0 >= cnt) return;
  __shared__ int toks[32];
  __shared__ f4 red[2][8][64];
  int tid = threadIdx.x;
  if (tid < 32)
    toks[tid] = (t0 + tid < cnt) ? ltok[e * N + t0 + tid] : -1;
  __syncthreads();
  int w = tid >> 6;
  int l = tid & 63;
  int lg = l >> 4, lr = l & 15;
  int tg = w >> 1, fh = w & 1;
  int slot = 16 * tg + lr;
  int tok = toks[slot];
  const h4* xp = (const h4*)(xh + (size_t)(tok < 0 ? 0 : tok) * D + 4 * lg);
  h4 xf[8];
#pragma unroll
  for (int kd = 0; kd < 8; ++kd) xf[kd] = xp[kd * 4];
  f4 oacc[8];
#pragma unroll
  for (int dt = 0; dt < 8; ++dt) oacc[dt] = (f4){0.f,0.f,0.f,0.f};
  const float* b1e = b1 + e * FF;
  const h4* w1b = (const h4*)w1pk + ((size_t)e * 32 + 16 * fh) * 8 * 64 + l;
  const h4* w2b = (const h4*)w2pk + ((size_t)e * 32 + 16 * fh) * 8 * 64 + l;
#pragma unroll 2
  for (int ftl = 0; ftl < 16; ++ftl) {
    f4 ha = {0.f,0.f,0.f,0.f};
#pragma unroll
    for (int kd = 0; kd < 8; ++kd)
      ha = MFMA16(w1b[(ftl * 8 + kd) * 64], xf[kd], ha, 0, 0, 0);
    int ft = 16 * fh + ftl;
    float4 bb = *(const float4*)&b1e[16 * ft + 4 * lg];
    h4 pf;
    {
      float z;
      z = ha.x + bb.x; pf.x = (_Float16)(0.5f * z * (1.f + erff(z * 0.70710678f)));
      z = ha.y + bb.y; pf.y = (_Float16)(0.5f * z * (1.f + erff(z * 0.70710678f)));
      z = ha.z + bb.z; pf.z = (_Float16)(0.5f * z * (1.f + erff(z * 0.70710678f)));
      z = ha.w + bb.w; pf.w = (_Float16)(0.5f * z * (1.f + erff(z * 0.70710678f)));
    }
#pragma unroll
    for (int dt = 0; dt < 8; ++dt)
      oacc[dt] = MFMA16(w2b[(ftl * 8 + dt) * 64], pf, oacc[dt], 0, 0, 0);
  }
  if (fh == 1) {
#pragma unroll
    for (int dt = 0; dt < 8; ++dt) red[tg][dt][l] = oacc[dt];
  }
  __syncthreads();
  if (fh == 0 && tok >= 0) {
    const float* b2e = b2 + e * D;
    float* eop = eo + ((size_t)(e * N + t0 + slot)) * 128;
#pragma unroll
    for (int dt = 0; dt < 8; ++dt) {
      f4 r = red[tg][dt][l];
      float4 bb = *(const float4*)&b2e[16 * dt + 4 * lg];
      float4 o4 = {oacc[dt].x + r.x + bb.x, oacc[dt].y + r.y + bb.y,
                   oacc[dt].z + r.z + bb.z, oacc[dt].w + r.w + bb.w};
      *(float4*)(eop + 16 * dt + 4 * lg) = o4;
    }
  }
}

// ---------------- finalize: out = x1 + g0*eo[i0] + g1*eo[i1]; aux ----------------
__global__ void finalize_kernel(const float* __restrict__ x1, const float* __restrict__ eo,
                                const int* __restrict__ sidx, const float* __restrict__ gwn,
                                const float* __restrict__ psum, const int* __restrict__ ecnt,
                                float* __restrict__ out) {
  int idx = blockIdx.x * 256 + threadIdx.x;   // float4 index, N*D/4 total
  int n = idx >> 5, d4 = idx & 31;
  int i0 = sidx[2*n], i1 = sidx[2*n+1];
  float g0 = gwn[2*n], g1 = gwn[2*n+1];
  float4 a = ((const float4*)x1)[idx];
  float4 u = ((const float4*)eo)[(size_t)i0 * 32 + d4];
  float4 w = ((const float4*)eo)[(size_t)i1 * 32 + d4];
  float4 o = {a.x + g0*u.x + g1*w.x, a.y + g0*u.y + g1*w.y,
              a.z + g0*u.z + g1*w.z, a.w + g0*u.w + g1*w.w};
  ((float4*)out)[idx] = o;
  if (idx == 0) {
    float aux = 0.f;
    for (int e = 0; e < E; ++e)
      aux += ((float)ecnt[e] * (1.f / 16384.f)) * (psum[e] * (1.f / 8192.f));
    out[N * D] = 8.f * aux;
  }
}

extern "C" void kernel_launch(void* const* d_in, const int* in_sizes, int n_in,
                              void* d_out, int out_size, void* d_ws, size_t ws_size,
                              hipStream_t stream) {
  const float* x    = (const float*)d_in[0];
  const float* ln1g = (const float*)d_in[1];
  const float* ln1b = (const float*)d_in[2];
  const float* wq   = (const float*)d_in[3];
  const float* wk   = (const float*)d_in[4];
  const float* wv   = (const float*)d_in[5];
  const float* wp   = (const float*)d_in[6];
  const float* bp   = (const float*)d_in[7];
  const float* ln2g = (const float*)d_in[8];
  const float* ln2b = (const float*)d_in[9];
  const float* wg   = (const float*)d_in[10];
  const float* w1   = (const float*)d_in[11];
  const float* b1   = (const float*)d_in[12];
  const float* w2   = (const float*)d_in[13];
  const float* b2   = (const float*)d_in[14];
  float* out = (float*)d_out;
  float* ws = (float*)d_ws;
  const size_t M = 1u << 20;  // 1M floats
  // layout (floats):
  // [0,1M)    A   : xn -> attn-out (f32)
  // [1M,2M)   Bq  : x1 (f32)
  // [2M,2.5M) qh f16 -> xh f16 (moe in)  [2.5M,3M) kh  [3M,3.5M) vTh
  // [3.5M,~12.94M) part ; eo reuses [3.5M,11.5M)
  // [12M,13M) xn2 f32 (written after part dead)
  // [13M,13.25M) w1pk  [13.25M,13.5M) w2pk
  // [13.5M,..) ltok/sidx/gwn/psum/ecnt/wcnt/wpsum/wbase/tokinfo/gws
  float* A  = ws;
  float* Bq = ws + 1 * M;
  _Float16* qh  = (_Float16*)(ws + 2 * M);
  _Float16* xh  = (_Float16*)(ws + 2 * M);       // reuses qh region
  _Float16* kh  = (_Float16*)(ws + 2 * M + M / 2);
  _Float16* vTh = (_Float16*)(ws + 3 * M);
  float* part = ws + 3 * M + M / 2;
  float* eo   = part;
  float* xn2  = ws + 12 * M;
  _Float16* w1pk = (_Float16*)(ws + 13 * M);
  _Float16* w2pk = (_Float16*)(ws + 13 * M + M / 4);
  size_t G0 = 13 * M + M / 2;
  int*    ltok   = (int*)(ws + G0);               // 65536 ints
  int*    sidx   = (int*)(ws + G0 + 65536);       // 16384 ints
  float*  gwn    = ws + G0 + 81920;               // 16384 floats
  float*  psum   = ws + G0 + 98304;               // 8
  int*    ecnt   = (int*)(ws + G0 + 98312);       // 8
  int*    wcnt   = (int*)(ws + G0 + 98320);       // 1024 ints
  float*  wpsum  = ws + G0 + 99344;               // 1024 floats
  int*    wbase  = (int*)(ws + G0 + 100368);      // 1024 ints
  int4*   tokinfo= (int4*)(ws + G0 + 101392);     // 8192 int4 = 32768 ints
  float2* gws    = (float2*)(ws + G0 + 134160);   // 8192 float2 = 16384 floats

  pack_w1<<<dim3(32, 8, E), 64, 0, stream>>>(w1, w1pk);
  pack_w2<<<dim3(32, 8, E), 64, 0, stream>>>(w2, w2pk);
  ln_kernel<<<N, 64, 0, stream>>>(x, ln1g, ln1b, A, nullptr);
  qkv_kernel<<<N / 16, 384, 0, stream>>>(A, wq, wk, wv, qh, kh, vTh);
  attn_mfma<<<dim3(32 * SPLITS, Bsz * H), 64, 0, stream>>>(qh, kh, vTh, part);
  attn_comb<<<NQ / 64, 64, 0, stream>>>(part, A);
  proj_kernel<<<N / 16, 128, 0, stream>>>(A, wp, bp, x, Bq);
  ln_kernel<<<N, 64, 0, stream>>>(Bq, ln2g, ln2b, xn2, xh);
  gate_part<<<N / 64, 64, 0, stream>>>(xn2, wg, wcnt, wpsum, tokinfo, gws);
  gate_scan<<<1, 64, 0, stream>>>(wcnt, wpsum, wbase, ecnt, psum);
  gate_scatter<<<N / 64, 64, 0, stream>>>(tokinfo, gws, wbase, ltok, sidx, gwn);
  moe_mfma<<<dim3(N / 32, E), 256, 0, stream>>>(xh, w1pk, b1, w2pk, b2, ecnt, ltok, eo);
  finalize_kernel<<<(N * D / 4) / 256, 256, 0, stream>>>(Bq, eo, sidx, gwn, psum, ecnt, out);
}